// Round 1
// baseline (612.661 us; speedup 1.0000x reference)
//
#include <hip/hip_runtime.h>
#include <hip/hip_bf16.h>

typedef unsigned short u16;
typedef unsigned int u32;
typedef __attribute__((ext_vector_type(8))) short bf16x8_t;   // MFMA A/B frag (8 bf16)
typedef __attribute__((ext_vector_type(4))) float f32x4_t;    // MFMA C/D frag
typedef __attribute__((ext_vector_type(8))) u16 u16x8;

// ---- problem constants ----
constexpr int B_  = 8;
constexpr int C_  = 512;
constexpr int NH_ = 16;
constexpr int HID_= 2048;
constexpr int Hh  = 56, Ww = 56;
constexpr int N_  = Hh * Ww;       // 3136
constexpr int M_  = B_ * N_;       // 25088 rows

__device__ __forceinline__ u16 f2bf(float f) {
    u32 u = __float_as_uint(f);
    u32 r = (u + 0x7fffu + ((u >> 16) & 1u)) >> 16;
    return (u16)r;
}
__device__ __forceinline__ float bf2f(u16 v) {
    return __uint_as_float(((u32)v) << 16);
}

__device__ __forceinline__ void gload_lds16(const void* g, void* l) {
    __builtin_amdgcn_global_load_lds(
        (const __attribute__((address_space(1))) u32*)g,
        (__attribute__((address_space(3))) u32*)l, 16, 0, 0);
}

// ------------------ weight fp32 -> bf16 conversion ------------------
__global__ void cvt_w(const float* __restrict__ qkvw, const float* __restrict__ fc1w,
                      const float* __restrict__ fc2w, u16* __restrict__ oq,
                      u16* __restrict__ o1, u16* __restrict__ o2) {
    int i = blockIdx.x * 256 + threadIdx.x;
    if (i < 3 * C_ * C_) oq[i] = f2bf(qkvw[i]);
    if (i < HID_ * C_) { o1[i] = f2bf(fc1w[i]); o2[i] = f2bf(fc2w[i]); }
}

// ------------------ LayerNorm (row=512) -> bf16 ------------------
__global__ __launch_bounds__(256) void ln_kernel(const float* __restrict__ x,
        const float* __restrict__ g, const float* __restrict__ b, u16* __restrict__ out) {
    int lane = threadIdx.x & 63, wv = threadIdx.x >> 6;
    size_t row = (size_t)blockIdx.x * 4 + wv;
    const float4* xr = (const float4*)(x + row * C_);
    float4 a = xr[lane * 2], c = xr[lane * 2 + 1];
    float s  = a.x + a.y + a.z + a.w + c.x + c.y + c.z + c.w;
    float ss = a.x*a.x + a.y*a.y + a.z*a.z + a.w*a.w + c.x*c.x + c.y*c.y + c.z*c.z + c.w*c.w;
    #pragma unroll
    for (int off = 1; off < 64; off <<= 1) {
        s  += __shfl_xor(s, off);
        ss += __shfl_xor(ss, off);
    }
    float mean = s * (1.0f / C_);
    float var  = ss * (1.0f / C_) - mean * mean;
    float rstd = rsqrtf(var + 1e-5f);
    const float4* g4 = (const float4*)g;
    const float4* b4 = (const float4*)b;
    float4 g0 = g4[lane*2], g1 = g4[lane*2+1], b0 = b4[lane*2], b1 = b4[lane*2+1];
    u16x8 o;
    o[0] = f2bf((a.x - mean) * rstd * g0.x + b0.x);
    o[1] = f2bf((a.y - mean) * rstd * g0.y + b0.y);
    o[2] = f2bf((a.z - mean) * rstd * g0.z + b0.z);
    o[3] = f2bf((a.w - mean) * rstd * g0.w + b0.w);
    o[4] = f2bf((c.x - mean) * rstd * g1.x + b1.x);
    o[5] = f2bf((c.y - mean) * rstd * g1.y + b1.y);
    o[6] = f2bf((c.z - mean) * rstd * g1.z + b1.z);
    o[7] = f2bf((c.w - mean) * rstd * g1.w + b1.w);
    *(u16x8*)&out[row * C_ + lane * 8] = o;
}

// ------------------ bf16 GEMM: C[M,N] = A[M,K] @ B[N,K]^T + bias (+res) ------------------
// 128x128 tile, BK=32, 256 threads = 4 waves, each wave 64x64 via 4x4 16x16x32 MFMAs.
template<bool RES, bool OUT_BF16>
__global__ __launch_bounds__(256) void gemm_bt(
        const u16* __restrict__ A, const u16* __restrict__ B,
        const float* __restrict__ bias, const float* __restrict__ res,
        void* __restrict__ Cout, int M, int N, int K) {
    __shared__ u16 As[128 * 32];
    __shared__ u16 Bs[128 * 32];
    const int tid = threadIdx.x;
    const int lane = tid & 63;
    const int wv = tid >> 6;
    const int bn = blockIdx.x, bm = blockIdx.y;

    const int r0 = lane >> 2;          // row within 16-row chunk
    const int kc = (lane & 3) * 8;     // k element offset within 32

    const u16* aBase = A + (size_t)(bm * 128) * K;
    const u16* bBase = B + (size_t)(bn * 128) * K;

    f32x4_t acc[4][4];
    f32x4_t zero = {0.f, 0.f, 0.f, 0.f};
    #pragma unroll
    for (int i = 0; i < 4; i++)
        #pragma unroll
        for (int j = 0; j < 4; j++) acc[i][j] = zero;

    const int mo = (wv >> 1) * 64, no = (wv & 1) * 64;
    const int fr = lane & 15;          // fragment row (m or n)
    const int fk = (lane >> 4) * 8;    // fragment k offset

    for (int k0 = 0; k0 < K; k0 += 32) {
        // stage A (8 chunks of 16 rows; wave w does chunks w and w+4)
        gload_lds16(aBase + (size_t)(wv * 16 + r0) * K + k0 + kc,       &As[(wv * 16) * 32]);
        gload_lds16(aBase + (size_t)((wv + 4) * 16 + r0) * K + k0 + kc, &As[((wv + 4) * 16) * 32]);
        gload_lds16(bBase + (size_t)(wv * 16 + r0) * K + k0 + kc,       &Bs[(wv * 16) * 32]);
        gload_lds16(bBase + (size_t)((wv + 4) * 16 + r0) * K + k0 + kc, &Bs[((wv + 4) * 16) * 32]);
        __syncthreads();

        bf16x8_t af[4], bfr[4];
        #pragma unroll
        for (int mt = 0; mt < 4; mt++)
            af[mt] = *(const bf16x8_t*)&As[(mo + mt * 16 + fr) * 32 + fk];
        #pragma unroll
        for (int nt = 0; nt < 4; nt++)
            bfr[nt] = *(const bf16x8_t*)&Bs[(no + nt * 16 + fr) * 32 + fk];
        #pragma unroll
        for (int mt = 0; mt < 4; mt++)
            #pragma unroll
            for (int nt = 0; nt < 4; nt++)
                acc[mt][nt] = __builtin_amdgcn_mfma_f32_16x16x32_bf16(af[mt], bfr[nt], acc[mt][nt], 0, 0, 0);
        __syncthreads();
    }

    // epilogue: C/D layout col=lane&15, row=(lane>>4)*4+r
    #pragma unroll
    for (int mt = 0; mt < 4; mt++) {
        #pragma unroll
        for (int r = 0; r < 4; r++) {
            int row = bm * 128 + mo + mt * 16 + (lane >> 4) * 4 + r;
            #pragma unroll
            for (int nt = 0; nt < 4; nt++) {
                int col = bn * 128 + no + nt * 16 + (lane & 15);
                float v = acc[mt][nt][r] + bias[col];
                if constexpr (RES) v += res[(size_t)row * N + col];
                if constexpr (OUT_BF16) ((u16*)Cout)[(size_t)row * N + col] = f2bf(v);
                else ((float*)Cout)[(size_t)row * N + col] = v;
            }
        }
    }
}

// ------------------ windowed attention, one block per (window, head) ------------------
__global__ __launch_bounds__(256) void attn_kernel(
        const u16* __restrict__ qkv, const float* __restrict__ rpb,
        const float* __restrict__ x, float* __restrict__ x2) {
    __shared__ u16 q_s[64 * 32];
    __shared__ u16 k_s[64 * 32];
    __shared__ u16 vT_s[32 * 64];
    __shared__ u16 p_s[64 * 64];
    const int tid = threadIdx.x, lane = tid & 63, wv = tid >> 6;
    const int wh = blockIdx.x;
    const int head = wh & 15, w = wh >> 4;
    const int b = w >> 6, win = w & 63, bh = win >> 3, bw = win & 7;

    // load q,k padded to 64 rows
    {
        int i = tid >> 2, dc = (tid & 3) * 8;
        if (i < 49) {
            int n = (bh * 7 + i / 7) * Ww + (bw * 7 + i % 7);
            const u16* base = qkv + ((size_t)(b * N_ + n)) * (3 * C_) + head * 32 + dc;
            *(u16x8*)&q_s[i * 32 + dc] = *(const u16x8*)(base);
            *(u16x8*)&k_s[i * 32 + dc] = *(const u16x8*)(base + C_);
        } else {
            u16x8 z = {0,0,0,0,0,0,0,0};
            *(u16x8*)&q_s[i * 32 + dc] = z;
            *(u16x8*)&k_s[i * 32 + dc] = z;
        }
    }
    // v transposed: vT[d][i]
    for (int f = tid; f < 64 * 32; f += 256) {
        int i = f >> 5, d = f & 31;
        u16 val = 0;
        if (i < 49) {
            int n = (bh * 7 + i / 7) * Ww + (bw * 7 + i % 7);
            val = qkv[((size_t)(b * N_ + n)) * (3 * C_) + 2 * C_ + head * 32 + d];
        }
        vT_s[d * 64 + i] = val;
    }
    __syncthreads();

    // S = q @ k^T (wave wv owns rows wv*16..+16)
    f32x4_t zero = {0.f, 0.f, 0.f, 0.f};
    f32x4_t s[4];
    bf16x8_t aq = *(const bf16x8_t*)&q_s[(wv * 16 + (lane & 15)) * 32 + (lane >> 4) * 8];
    #pragma unroll
    for (int nt = 0; nt < 4; nt++) {
        bf16x8_t bk = *(const bf16x8_t*)&k_s[(nt * 16 + (lane & 15)) * 32 + (lane >> 4) * 8];
        s[nt] = __builtin_amdgcn_mfma_f32_16x16x32_bf16(aq, bk, zero, 0, 0, 0);
    }

    const float scale = 0.17677669529663687f; // 32^-0.5
    #pragma unroll
    for (int r = 0; r < 4; r++) {
        int row = wv * 16 + (lane >> 4) * 4 + r;
        int qy = row / 7, qx = row - qy * 7;
        float pv[4];
        float m = -1e30f;
        #pragma unroll
        for (int nt = 0; nt < 4; nt++) {
            int col = nt * 16 + (lane & 15);
            float bias;
            if (row < 49 && col < 49) {
                int ky = col / 7, kx = col - ky * 7;
                bias = rpb[((qy - ky + 6) * 13 + (qx - kx + 6)) * NH_ + head];
            } else bias = -1e30f;
            float v = s[nt][r] * scale + bias;
            pv[nt] = v;
            m = fmaxf(m, v);
        }
        #pragma unroll
        for (int off = 1; off < 16; off <<= 1) m = fmaxf(m, __shfl_xor(m, off));
        float sum = 0.f;
        #pragma unroll
        for (int nt = 0; nt < 4; nt++) { pv[nt] = __expf(pv[nt] - m); sum += pv[nt]; }
        #pragma unroll
        for (int off = 1; off < 16; off <<= 1) sum += __shfl_xor(sum, off);
        float inv = 1.0f / sum;
        #pragma unroll
        for (int nt = 0; nt < 4; nt++)
            p_s[row * 64 + nt * 16 + (lane & 15)] = f2bf(pv[nt] * inv);
    }
    __syncthreads();

    // O = P @ V (rows wv*16..+16, cols 0..31)
    f32x4_t o[2] = {zero, zero};
    #pragma unroll
    for (int kt = 0; kt < 2; kt++) {
        bf16x8_t ap = *(const bf16x8_t*)&p_s[(wv * 16 + (lane & 15)) * 64 + kt * 32 + (lane >> 4) * 8];
        #pragma unroll
        for (int nt = 0; nt < 2; nt++) {
            bf16x8_t bv = *(const bf16x8_t*)&vT_s[(nt * 16 + (lane & 15)) * 64 + kt * 32 + (lane >> 4) * 8];
            o[nt] = __builtin_amdgcn_mfma_f32_16x16x32_bf16(ap, bv, o[nt], 0, 0, 0);
        }
    }
    #pragma unroll
    for (int nt = 0; nt < 2; nt++) {
        #pragma unroll
        for (int r = 0; r < 4; r++) {
            int row = wv * 16 + (lane >> 4) * 4 + r;
            if (row < 49) {
                int n = (bh * 7 + row / 7) * Ww + (bw * 7 + row % 7);
                int col = head * 32 + nt * 16 + (lane & 15);
                size_t idx = ((size_t)(b * N_ + n)) * C_ + col;
                x2[idx] = x[idx] + o[nt][r];
            }
        }
    }
}

// ------------------ depthwise 3x3 conv + bias + exact GELU ------------------
// block = (b, y, half); thread t: channels t*8..t*8+7; x in [half*28, half*28+28)
__global__ __launch_bounds__(256) void dwconv_gelu(const u16* __restrict__ in,
        const float* __restrict__ w, const float* __restrict__ bias, u16* __restrict__ out) {
    const int t = threadIdx.x;
    const int blk = blockIdx.x;
    const int half = blk & 1;
    const int by = blk >> 1;
    const int y = by % Hh;
    const int b = by / Hh;
    const int c0 = t * 8;

    float wr[9][8];
    #pragma unroll
    for (int k = 0; k < 9; k++)
        #pragma unroll
        for (int j = 0; j < 8; j++) wr[k][j] = w[(c0 + j) * 9 + k];
    float bs[8];
    #pragma unroll
    for (int j = 0; j < 8; j++) bs[j] = bias[c0 + j];

    u16x8 zerov = {0,0,0,0,0,0,0,0};
    auto ldcol = [&](int xx, u16x8 col[3]) {
        #pragma unroll
        for (int dy = 0; dy < 3; dy++) {
            int yy = y + dy - 1;
            bool ok = (yy >= 0 && yy < Hh && xx >= 0 && xx < Ww);
            col[dy] = ok ? *(const u16x8*)&in[(((size_t)b * Hh + yy) * Ww + xx) * HID_ + c0] : zerov;
        }
    };

    int xs = half * 28;
    u16x8 wA[3], wB[3], wC[3];
    ldcol(xs - 1, wA);
    ldcol(xs, wB);
    for (int x = xs; x < xs + 28; x++) {
        ldcol(x + 1, wC);
        float acc[8];
        #pragma unroll
        for (int j = 0; j < 8; j++) acc[j] = bs[j];
        #pragma unroll
        for (int dy = 0; dy < 3; dy++)
            #pragma unroll
            for (int j = 0; j < 8; j++) {
                acc[j] += bf2f(wA[dy][j]) * wr[dy * 3 + 0][j];
                acc[j] += bf2f(wB[dy][j]) * wr[dy * 3 + 1][j];
                acc[j] += bf2f(wC[dy][j]) * wr[dy * 3 + 2][j];
            }
        u16x8 o;
        #pragma unroll
        for (int j = 0; j < 8; j++) {
            float v = acc[j];
            v = 0.5f * v * (1.0f + erff(v * 0.70710678118654752f));
            o[j] = f2bf(v);
        }
        *(u16x8*)&out[(((size_t)b * Hh + y) * Ww + x) * HID_ + c0] = o;
        #pragma unroll
        for (int dy = 0; dy < 3; dy++) { wA[dy] = wB[dy]; wB[dy] = wC[dy]; }
    }
}

// ------------------ launch ------------------
extern "C" void kernel_launch(void* const* d_in, const int* in_sizes, int n_in,
                              void* d_out, int out_size, void* d_ws, size_t ws_size,
                              hipStream_t stream) {
    const float* x    = (const float*)d_in[0];
    const float* n1g  = (const float*)d_in[3];
    const float* n1b  = (const float*)d_in[4];
    const float* n2g  = (const float*)d_in[5];
    const float* n2b  = (const float*)d_in[6];
    const float* qkvw = (const float*)d_in[7];
    const float* qkvb = (const float*)d_in[8];
    const float* rpb  = (const float*)d_in[9];
    const float* fc1w = (const float*)d_in[10];
    const float* fc1b = (const float*)d_in[11];
    const float* dww  = (const float*)d_in[12];
    const float* dwb  = (const float*)d_in[13];
    const float* fc2w = (const float*)d_in[14];
    const float* fc2b = (const float*)d_in[15];

    char* ws = (char*)d_ws;
    // layout (bytes):
    // x2   : [0, 51380224)                    fp32 [M,512]
    // h    : [51380224, 77070336)             bf16 [M,512]   (LN1 out, then LN2 out)
    // qkv  : [77070336, 154140672)            bf16 [M,1536]
    // f1o  : [154140672, 256901120)           bf16 [M,2048]
    // cvo  : [51380224, 154140672)            bf16 [M,2048]  (reuses h+qkv after fc1)
    // wbf  : [256901120, ...)                 bf16 weights
    float* x2  = (float*)(ws);
    u16*   h   = (u16*)(ws + 51380224);
    u16*   qkvo= (u16*)(ws + 77070336);
    u16*   f1o = (u16*)(ws + 154140672);
    u16*   cvo = (u16*)(ws + 51380224);
    u16*   wq  = (u16*)(ws + 256901120);
    u16*   w1  = (u16*)(ws + 256901120 + 1572864);
    u16*   w2  = (u16*)(ws + 256901120 + 1572864 + 2097152);

    cvt_w<<<dim3(4096), dim3(256), 0, stream>>>(qkvw, fc1w, fc2w, wq, w1, w2);
    ln_kernel<<<dim3(M_ / 4), dim3(256), 0, stream>>>(x, n1g, n1b, h);
    gemm_bt<false, true><<<dim3(1536 / 128, M_ / 128), dim3(256), 0, stream>>>(
        h, wq, qkvb, nullptr, (void*)qkvo, M_, 1536, 512);
    attn_kernel<<<dim3(B_ * 64 * NH_), dim3(256), 0, stream>>>(qkvo, rpb, x, x2);
    ln_kernel<<<dim3(M_ / 4), dim3(256), 0, stream>>>(x2, n2g, n2b, h);
    gemm_bt<false, true><<<dim3(2048 / 128, M_ / 128), dim3(256), 0, stream>>>(
        h, w1, fc1b, nullptr, (void*)f1o, M_, 2048, 512);
    dwconv_gelu<<<dim3(B_ * Hh * 2), dim3(256), 0, stream>>>(f1o, dww, dwb, cvo);
    gemm_bt<true, false><<<dim3(512 / 128, M_ / 128), dim3(256), 0, stream>>>(
        cvo, w2, fc2b, x2, d_out, M_, 512, 2048);
}

// Round 2
// 599.892 us; speedup vs baseline: 1.0213x; 1.0213x over previous
//
#include <hip/hip_runtime.h>
#include <hip/hip_bf16.h>

typedef unsigned short u16;
typedef unsigned int u32;
typedef __attribute__((ext_vector_type(8))) short bf16x8_t;   // MFMA A/B frag (8 bf16)
typedef __attribute__((ext_vector_type(4))) float f32x4_t;    // MFMA C/D frag
typedef __attribute__((ext_vector_type(8))) u16 u16x8;

// ---- problem constants ----
constexpr int B_  = 8;
constexpr int C_  = 512;
constexpr int NH_ = 16;
constexpr int HID_= 2048;
constexpr int Hh  = 56, Ww = 56;
constexpr int N_  = Hh * Ww;       // 3136
constexpr int M_  = B_ * N_;       // 25088 rows

__device__ __forceinline__ u16 f2bf(float f) {
    u32 u = __float_as_uint(f);
    u32 r = (u + 0x7fffu + ((u >> 16) & 1u)) >> 16;
    return (u16)r;
}
__device__ __forceinline__ float bf2f(u16 v) {
    return __uint_as_float(((u32)v) << 16);
}

__device__ __forceinline__ void gload_lds16(const void* g, void* l) {
    __builtin_amdgcn_global_load_lds(
        (const __attribute__((address_space(1))) u32*)g,
        (__attribute__((address_space(3))) u32*)l, 16, 0, 0);
}

// ------------------ weight fp32 -> bf16 conversion ------------------
__global__ void cvt_w(const float* __restrict__ qkvw, const float* __restrict__ fc1w,
                      const float* __restrict__ fc2w, u16* __restrict__ oq,
                      u16* __restrict__ o1, u16* __restrict__ o2) {
    int i = blockIdx.x * 256 + threadIdx.x;
    if (i < 3 * C_ * C_) oq[i] = f2bf(qkvw[i]);
    if (i < HID_ * C_) { o1[i] = f2bf(fc1w[i]); o2[i] = f2bf(fc2w[i]); }
}

// ------------------ LayerNorm (row=512) -> bf16 ------------------
__global__ __launch_bounds__(256) void ln_kernel(const float* __restrict__ x,
        const float* __restrict__ g, const float* __restrict__ b, u16* __restrict__ out) {
    int lane = threadIdx.x & 63, wv = threadIdx.x >> 6;
    size_t row = (size_t)blockIdx.x * 4 + wv;
    const float4* xr = (const float4*)(x + row * C_);
    float4 a = xr[lane * 2], c = xr[lane * 2 + 1];
    float s  = a.x + a.y + a.z + a.w + c.x + c.y + c.z + c.w;
    float ss = a.x*a.x + a.y*a.y + a.z*a.z + a.w*a.w + c.x*c.x + c.y*c.y + c.z*c.z + c.w*c.w;
    #pragma unroll
    for (int off = 1; off < 64; off <<= 1) {
        s  += __shfl_xor(s, off);
        ss += __shfl_xor(ss, off);
    }
    float mean = s * (1.0f / C_);
    float var  = ss * (1.0f / C_) - mean * mean;
    float rstd = rsqrtf(var + 1e-5f);
    const float4* g4 = (const float4*)g;
    const float4* b4 = (const float4*)b;
    float4 g0 = g4[lane*2], g1 = g4[lane*2+1], b0 = b4[lane*2], b1 = b4[lane*2+1];
    u16x8 o;
    o[0] = f2bf((a.x - mean) * rstd * g0.x + b0.x);
    o[1] = f2bf((a.y - mean) * rstd * g0.y + b0.y);
    o[2] = f2bf((a.z - mean) * rstd * g0.z + b0.z);
    o[3] = f2bf((a.w - mean) * rstd * g0.w + b0.w);
    o[4] = f2bf((c.x - mean) * rstd * g1.x + b1.x);
    o[5] = f2bf((c.y - mean) * rstd * g1.y + b1.y);
    o[6] = f2bf((c.z - mean) * rstd * g1.z + b1.z);
    o[7] = f2bf((c.w - mean) * rstd * g1.w + b1.w);
    *(u16x8*)&out[row * C_ + lane * 8] = o;
}

// ------------------ bf16 GEMM: C[M,N] = A[M,K] @ B[N,K]^T + bias (+res) ------------------
// 128x128 tile, BK=64 as two 32-k planes, 256 threads = 4 waves, each wave 64x64.
// LDS k-chunks XOR-swizzled: slot = chunk ^ ((row>>1)&3)  -> 2-way bank aliasing (free).
// grid: x = bm (fast) so concurrent blocks share the small B weight tile in L2.
template<bool RES, bool OUT_BF16>
__global__ __launch_bounds__(256) void gemm_bt(
        const u16* __restrict__ A, const u16* __restrict__ B,
        const float* __restrict__ bias, const float* __restrict__ res,
        void* __restrict__ Cout, int M, int N, int K) {
    __shared__ __align__(16) u16 As[2 * 128 * 32];
    __shared__ __align__(16) u16 Bs[2 * 128 * 32];
    const int tid = threadIdx.x;
    const int lane = tid & 63;
    const int wv = tid >> 6;
    const int bm = blockIdx.x, bn = blockIdx.y;

    const int r0 = lane >> 2;                          // staging row within 16-row group
    const int gcb = ((lane & 3) ^ ((lane >> 3) & 3));  // swizzled global chunk for this lane

    const u16* aBase = A + (size_t)(bm * 128) * K;
    const u16* bBase = B + (size_t)(bn * 128) * K;

    f32x4_t acc[4][4];
    f32x4_t zero = {0.f, 0.f, 0.f, 0.f};
    #pragma unroll
    for (int i = 0; i < 4; i++)
        #pragma unroll
        for (int j = 0; j < 4; j++) acc[i][j] = zero;

    const int mo = (wv >> 1) * 64, no = (wv & 1) * 64;
    const int fr = lane & 15;          // fragment row (m or n)
    const int g4 = lane >> 4;          // k-chunk index within 32-k plane
    const int kkey = (fr >> 1) & 3;    // swizzle key
    const int pos = (g4 ^ kkey) * 8;   // swizzled element offset within row

    for (int k0 = 0; k0 < K; k0 += 64) {
        #pragma unroll
        for (int p = 0; p < 2; p++) {
            const int ko = k0 + p * 32 + gcb * 8;
            gload_lds16(aBase + (size_t)(wv * 16 + r0) * K + ko,       &As[p * 4096 + (wv * 16) * 32]);
            gload_lds16(aBase + (size_t)((wv + 4) * 16 + r0) * K + ko, &As[p * 4096 + ((wv + 4) * 16) * 32]);
            gload_lds16(bBase + (size_t)(wv * 16 + r0) * K + ko,       &Bs[p * 4096 + (wv * 16) * 32]);
            gload_lds16(bBase + (size_t)((wv + 4) * 16 + r0) * K + ko, &Bs[p * 4096 + ((wv + 4) * 16) * 32]);
        }
        __syncthreads();

        #pragma unroll
        for (int ks = 0; ks < 2; ks++) {
            bf16x8_t af[4], bfr[4];
            #pragma unroll
            for (int mt = 0; mt < 4; mt++)
                af[mt] = *(const bf16x8_t*)&As[ks * 4096 + (mo + mt * 16 + fr) * 32 + pos];
            #pragma unroll
            for (int nt = 0; nt < 4; nt++)
                bfr[nt] = *(const bf16x8_t*)&Bs[ks * 4096 + (no + nt * 16 + fr) * 32 + pos];
            #pragma unroll
            for (int mt = 0; mt < 4; mt++)
                #pragma unroll
                for (int nt = 0; nt < 4; nt++)
                    acc[mt][nt] = __builtin_amdgcn_mfma_f32_16x16x32_bf16(af[mt], bfr[nt], acc[mt][nt], 0, 0, 0);
        }
        __syncthreads();
    }

    // epilogue: C/D layout col=lane&15, row=(lane>>4)*4+r
    #pragma unroll
    for (int mt = 0; mt < 4; mt++) {
        #pragma unroll
        for (int r = 0; r < 4; r++) {
            int row = bm * 128 + mo + mt * 16 + (lane >> 4) * 4 + r;
            #pragma unroll
            for (int nt = 0; nt < 4; nt++) {
                int col = bn * 128 + no + nt * 16 + (lane & 15);
                float v = acc[mt][nt][r] + bias[col];
                if constexpr (RES) v += res[(size_t)row * N + col];
                if constexpr (OUT_BF16) ((u16*)Cout)[(size_t)row * N + col] = f2bf(v);
                else ((float*)Cout)[(size_t)row * N + col] = v;
            }
        }
    }
}

// ------------------ windowed attention, one block per (window, head) ------------------
constexpr int QS = 40;  // q/k row stride (u16), padded +8
constexpr int VS = 72;  // vT row stride
constexpr int PS = 72;  // p row stride

__global__ __launch_bounds__(256) void attn_kernel(
        const u16* __restrict__ qkv, const float* __restrict__ rpb,
        const float* __restrict__ x, float* __restrict__ x2) {
    __shared__ __align__(16) u16 q_s[64 * QS];
    __shared__ __align__(16) u16 k_s[64 * QS];
    __shared__ __align__(16) u16 vT_s[32 * VS];
    __shared__ __align__(16) u16 p_s[64 * PS];
    const int tid = threadIdx.x, lane = tid & 63, wv = tid >> 6;
    const int wh = blockIdx.x;
    const int head = wh & 15, w = wh >> 4;
    const int b = w >> 6, win = w & 63, bh = win >> 3, bw = win & 7;

    // load q,k padded to 64 rows
    {
        int i = tid >> 2, dc = (tid & 3) * 8;
        if (i < 49) {
            int n = (bh * 7 + i / 7) * Ww + (bw * 7 + i % 7);
            const u16* base = qkv + ((size_t)(b * N_ + n)) * (3 * C_) + head * 32 + dc;
            *(u16x8*)&q_s[i * QS + dc] = *(const u16x8*)(base);
            *(u16x8*)&k_s[i * QS + dc] = *(const u16x8*)(base + C_);
        } else {
            u16x8 z = {0,0,0,0,0,0,0,0};
            *(u16x8*)&q_s[i * QS + dc] = z;
            *(u16x8*)&k_s[i * QS + dc] = z;
        }
    }
    // v transposed: vT[d][i]
    for (int f = tid; f < 64 * 32; f += 256) {
        int i = f >> 5, d = f & 31;
        u16 val = 0;
        if (i < 49) {
            int n = (bh * 7 + i / 7) * Ww + (bw * 7 + i % 7);
            val = qkv[((size_t)(b * N_ + n)) * (3 * C_) + 2 * C_ + head * 32 + d];
        }
        vT_s[d * VS + i] = val;
    }
    __syncthreads();

    // S = q @ k^T (wave wv owns rows wv*16..+16)
    f32x4_t zero = {0.f, 0.f, 0.f, 0.f};
    f32x4_t s[4];
    bf16x8_t aq = *(const bf16x8_t*)&q_s[(wv * 16 + (lane & 15)) * QS + (lane >> 4) * 8];
    #pragma unroll
    for (int nt = 0; nt < 4; nt++) {
        bf16x8_t bk = *(const bf16x8_t*)&k_s[(nt * 16 + (lane & 15)) * QS + (lane >> 4) * 8];
        s[nt] = __builtin_amdgcn_mfma_f32_16x16x32_bf16(aq, bk, zero, 0, 0, 0);
    }

    const float scale = 0.17677669529663687f; // 32^-0.5
    #pragma unroll
    for (int r = 0; r < 4; r++) {
        int row = wv * 16 + (lane >> 4) * 4 + r;
        int qy = row / 7, qx = row - qy * 7;
        float pv[4];
        float m = -1e30f;
        #pragma unroll
        for (int nt = 0; nt < 4; nt++) {
            int col = nt * 16 + (lane & 15);
            float bias;
            if (row < 49 && col < 49) {
                int ky = col / 7, kx = col - ky * 7;
                bias = rpb[((qy - ky + 6) * 13 + (qx - kx + 6)) * NH_ + head];
            } else bias = -1e30f;
            float v = s[nt][r] * scale + bias;
            pv[nt] = v;
            m = fmaxf(m, v);
        }
        #pragma unroll
        for (int off = 1; off < 16; off <<= 1) m = fmaxf(m, __shfl_xor(m, off));
        float sum = 0.f;
        #pragma unroll
        for (int nt = 0; nt < 4; nt++) { pv[nt] = __expf(pv[nt] - m); sum += pv[nt]; }
        #pragma unroll
        for (int off = 1; off < 16; off <<= 1) sum += __shfl_xor(sum, off);
        float inv = 1.0f / sum;
        #pragma unroll
        for (int nt = 0; nt < 4; nt++)
            p_s[row * PS + nt * 16 + (lane & 15)] = f2bf(pv[nt] * inv);
    }
    __syncthreads();

    // O = P @ V (rows wv*16..+16, cols 0..31)
    f32x4_t o[2] = {zero, zero};
    #pragma unroll
    for (int kt = 0; kt < 2; kt++) {
        bf16x8_t ap = *(const bf16x8_t*)&p_s[(wv * 16 + (lane & 15)) * PS + kt * 32 + (lane >> 4) * 8];
        #pragma unroll
        for (int nt = 0; nt < 2; nt++) {
            bf16x8_t bv = *(const bf16x8_t*)&vT_s[(nt * 16 + (lane & 15)) * VS + kt * 32 + (lane >> 4) * 8];
            o[nt] = __builtin_amdgcn_mfma_f32_16x16x32_bf16(ap, bv, o[nt], 0, 0, 0);
        }
    }
    #pragma unroll
    for (int nt = 0; nt < 2; nt++) {
        #pragma unroll
        for (int r = 0; r < 4; r++) {
            int row = wv * 16 + (lane >> 4) * 4 + r;
            if (row < 49) {
                int n = (bh * 7 + row / 7) * Ww + (bw * 7 + row % 7);
                int col = head * 32 + nt * 16 + (lane & 15);
                size_t idx = ((size_t)(b * N_ + n)) * C_ + col;
                x2[idx] = x[idx] + o[nt][r];
            }
        }
    }
}

// ------------------ depthwise 3x3 conv + bias + exact GELU ------------------
__global__ __launch_bounds__(256) void dwconv_gelu(const u16* __restrict__ in,
        const float* __restrict__ w, const float* __restrict__ bias, u16* __restrict__ out) {
    const int t = threadIdx.x;
    const int blk = blockIdx.x;
    const int half = blk & 1;
    const int by = blk >> 1;
    const int y = by % Hh;
    const int b = by / Hh;
    const int c0 = t * 8;

    float wr[9][8];
    #pragma unroll
    for (int k = 0; k < 9; k++)
        #pragma unroll
        for (int j = 0; j < 8; j++) wr[k][j] = w[(c0 + j) * 9 + k];
    float bs[8];
    #pragma unroll
    for (int j = 0; j < 8; j++) bs[j] = bias[c0 + j];

    u16x8 zerov = {0,0,0,0,0,0,0,0};
    auto ldcol = [&](int xx, u16x8 col[3]) {
        #pragma unroll
        for (int dy = 0; dy < 3; dy++) {
            int yy = y + dy - 1;
            bool ok = (yy >= 0 && yy < Hh && xx >= 0 && xx < Ww);
            col[dy] = ok ? *(const u16x8*)&in[(((size_t)b * Hh + yy) * Ww + xx) * HID_ + c0] : zerov;
        }
    };

    int xs = half * 28;
    u16x8 wA[3], wB[3], wC[3];
    ldcol(xs - 1, wA);
    ldcol(xs, wB);
    for (int x = xs; x < xs + 28; x++) {
        ldcol(x + 1, wC);
        float acc[8];
        #pragma unroll
        for (int j = 0; j < 8; j++) acc[j] = bs[j];
        #pragma unroll
        for (int dy = 0; dy < 3; dy++)
            #pragma unroll
            for (int j = 0; j < 8; j++) {
                acc[j] += bf2f(wA[dy][j]) * wr[dy * 3 + 0][j];
                acc[j] += bf2f(wB[dy][j]) * wr[dy * 3 + 1][j];
                acc[j] += bf2f(wC[dy][j]) * wr[dy * 3 + 2][j];
            }
        u16x8 o;
        #pragma unroll
        for (int j = 0; j < 8; j++) {
            float v = acc[j];
            v = 0.5f * v * (1.0f + erff(v * 0.70710678118654752f));
            o[j] = f2bf(v);
        }
        *(u16x8*)&out[(((size_t)b * Hh + y) * Ww + x) * HID_ + c0] = o;
        #pragma unroll
        for (int dy = 0; dy < 3; dy++) { wA[dy] = wB[dy]; wB[dy] = wC[dy]; }
    }
}

// ------------------ launch ------------------
extern "C" void kernel_launch(void* const* d_in, const int* in_sizes, int n_in,
                              void* d_out, int out_size, void* d_ws, size_t ws_size,
                              hipStream_t stream) {
    const float* x    = (const float*)d_in[0];
    const float* n1g  = (const float*)d_in[3];
    const float* n1b  = (const float*)d_in[4];
    const float* n2g  = (const float*)d_in[5];
    const float* n2b  = (const float*)d_in[6];
    const float* qkvw = (const float*)d_in[7];
    const float* qkvb = (const float*)d_in[8];
    const float* rpb  = (const float*)d_in[9];
    const float* fc1w = (const float*)d_in[10];
    const float* fc1b = (const float*)d_in[11];
    const float* dww  = (const float*)d_in[12];
    const float* dwb  = (const float*)d_in[13];
    const float* fc2w = (const float*)d_in[14];
    const float* fc2b = (const float*)d_in[15];

    char* ws = (char*)d_ws;
    float* x2  = (float*)(ws);
    u16*   h   = (u16*)(ws + 51380224);
    u16*   qkvo= (u16*)(ws + 77070336);
    u16*   f1o = (u16*)(ws + 154140672);
    u16*   cvo = (u16*)(ws + 51380224);
    u16*   wq  = (u16*)(ws + 256901120);
    u16*   w1  = (u16*)(ws + 256901120 + 1572864);
    u16*   w2  = (u16*)(ws + 256901120 + 1572864 + 2097152);

    cvt_w<<<dim3(4096), dim3(256), 0, stream>>>(qkvw, fc1w, fc2w, wq, w1, w2);
    ln_kernel<<<dim3(M_ / 4), dim3(256), 0, stream>>>(x, n1g, n1b, h);
    gemm_bt<false, true><<<dim3(M_ / 128, 1536 / 128), dim3(256), 0, stream>>>(
        h, wq, qkvb, nullptr, (void*)qkvo, M_, 1536, 512);
    attn_kernel<<<dim3(B_ * 64 * NH_), dim3(256), 0, stream>>>(qkvo, rpb, x, x2);
    ln_kernel<<<dim3(M_ / 4), dim3(256), 0, stream>>>(x2, n2g, n2b, h);
    gemm_bt<false, true><<<dim3(M_ / 128, 2048 / 128), dim3(256), 0, stream>>>(
        h, w1, fc1b, nullptr, (void*)f1o, M_, 2048, 512);
    dwconv_gelu<<<dim3(B_ * Hh * 2), dim3(256), 0, stream>>>(f1o, dww, dwb, cvo);
    gemm_bt<true, false><<<dim3(M_ / 128, 512 / 128), dim3(256), 0, stream>>>(
        cvo, w2, fc2b, x2, d_out, M_, 512, 2048);
}

// Round 3
// 575.554 us; speedup vs baseline: 1.0645x; 1.0423x over previous
//
#include <hip/hip_runtime.h>
#include <hip/hip_bf16.h>

typedef unsigned short u16;
typedef unsigned int u32;
typedef __attribute__((ext_vector_type(8))) short bf16x8_t;   // MFMA A/B frag (8 bf16)
typedef __attribute__((ext_vector_type(4))) float f32x4_t;    // MFMA C/D frag
typedef __attribute__((ext_vector_type(8))) u16 u16x8;

// ---- problem constants ----
constexpr int B_  = 8;
constexpr int C_  = 512;
constexpr int NH_ = 16;
constexpr int HID_= 2048;
constexpr int Hh  = 56, Ww = 56;
constexpr int N_  = Hh * Ww;       // 3136
constexpr int M_  = B_ * N_;       // 25088 rows

__device__ __forceinline__ u16 f2bf(float f) {
    u32 u = __float_as_uint(f);
    u32 r = (u + 0x7fffu + ((u >> 16) & 1u)) >> 16;
    return (u16)r;
}
__device__ __forceinline__ float bf2f(u16 v) {
    return __uint_as_float(((u32)v) << 16);
}

__device__ __forceinline__ void gload_lds16(const void* g, void* l) {
    __builtin_amdgcn_global_load_lds(
        (const __attribute__((address_space(1))) u32*)g,
        (__attribute__((address_space(3))) u32*)l, 16, 0, 0);
}

// ------------------ weight fp32 -> bf16 conversion ------------------
__global__ void cvt_w(const float* __restrict__ qkvw, const float* __restrict__ fc1w,
                      const float* __restrict__ fc2w, u16* __restrict__ oq,
                      u16* __restrict__ o1, u16* __restrict__ o2) {
    int i = blockIdx.x * 256 + threadIdx.x;
    if (i < 3 * C_ * C_) oq[i] = f2bf(qkvw[i]);
    if (i < HID_ * C_) { o1[i] = f2bf(fc1w[i]); o2[i] = f2bf(fc2w[i]); }
}

// ------------------ LayerNorm (row=512) -> bf16 ------------------
__global__ __launch_bounds__(256) void ln_kernel(const float* __restrict__ x,
        const float* __restrict__ g, const float* __restrict__ b, u16* __restrict__ out) {
    int lane = threadIdx.x & 63, wv = threadIdx.x >> 6;
    size_t row = (size_t)blockIdx.x * 4 + wv;
    const float4* xr = (const float4*)(x + row * C_);
    float4 a = xr[lane * 2], c = xr[lane * 2 + 1];
    float s  = a.x + a.y + a.z + a.w + c.x + c.y + c.z + c.w;
    float ss = a.x*a.x + a.y*a.y + a.z*a.z + a.w*a.w + c.x*c.x + c.y*c.y + c.z*c.z + c.w*c.w;
    #pragma unroll
    for (int off = 1; off < 64; off <<= 1) {
        s  += __shfl_xor(s, off);
        ss += __shfl_xor(ss, off);
    }
    float mean = s * (1.0f / C_);
    float var  = ss * (1.0f / C_) - mean * mean;
    float rstd = rsqrtf(var + 1e-5f);
    const float4* g4 = (const float4*)g;
    const float4* b4 = (const float4*)b;
    float4 g0 = g4[lane*2], g1 = g4[lane*2+1], b0 = b4[lane*2], b1 = b4[lane*2+1];
    u16x8 o;
    o[0] = f2bf((a.x - mean) * rstd * g0.x + b0.x);
    o[1] = f2bf((a.y - mean) * rstd * g0.y + b0.y);
    o[2] = f2bf((a.z - mean) * rstd * g0.z + b0.z);
    o[3] = f2bf((a.w - mean) * rstd * g0.w + b0.w);
    o[4] = f2bf((c.x - mean) * rstd * g1.x + b1.x);
    o[5] = f2bf((c.y - mean) * rstd * g1.y + b1.y);
    o[6] = f2bf((c.z - mean) * rstd * g1.z + b1.z);
    o[7] = f2bf((c.w - mean) * rstd * g1.w + b1.w);
    *(u16x8*)&out[row * C_ + lane * 8] = o;
}

// ------------------ bf16 GEMM: C[M,N] = A[M,K] @ B[N,K]^T + bias (+res) ------------------
// 128x128 tile, BK=32, double-buffered LDS (2x16KB), prefetch-after-barrier.
// Per iter: stage(next buf) -> compute(cur buf) -> barrier. The vmcnt(0) drain at the
// barrier lands after the compute phase, hiding most of the load latency.
// XOR-swizzled k-chunks (verified conflict-free in round 2).
template<bool RES, bool OUT_BF16>
__global__ __launch_bounds__(256) void gemm_bt(
        const u16* __restrict__ A, const u16* __restrict__ B,
        const float* __restrict__ bias, const float* __restrict__ res,
        void* __restrict__ Cout, int M, int N, int K) {
    __shared__ __align__(16) u16 As[2][128 * 32];
    __shared__ __align__(16) u16 Bs[2][128 * 32];
    const int tid = threadIdx.x;
    const int lane = tid & 63;
    const int wv = tid >> 6;
    const int bm = blockIdx.x, bn = blockIdx.y;

    const int r0 = lane >> 2;                          // staging row within 16-row group
    const int gcb = ((lane & 3) ^ ((lane >> 3) & 3));  // swizzled global chunk for this lane

    const u16* aBase = A + (size_t)(bm * 128) * K;
    const u16* bBase = B + (size_t)(bn * 128) * K;

    f32x4_t acc[4][4];
    f32x4_t zero = {0.f, 0.f, 0.f, 0.f};
    #pragma unroll
    for (int i = 0; i < 4; i++)
        #pragma unroll
        for (int j = 0; j < 4; j++) acc[i][j] = zero;

    const int mo = (wv >> 1) * 64, no = (wv & 1) * 64;
    const int fr = lane & 15;          // fragment row (m or n)
    const int g4 = lane >> 4;          // k-chunk index within 32-k plane
    const int kkey = (fr >> 1) & 3;    // swizzle key
    const int pos = (g4 ^ kkey) * 8;   // swizzled element offset within row

    auto stage = [&](int buf, int k0) {
        const int ko = k0 + gcb * 8;
        gload_lds16(aBase + (size_t)(wv * 16 + r0) * K + ko,       &As[buf][(wv * 16) * 32]);
        gload_lds16(aBase + (size_t)((wv + 4) * 16 + r0) * K + ko, &As[buf][((wv + 4) * 16) * 32]);
        gload_lds16(bBase + (size_t)(wv * 16 + r0) * K + ko,       &Bs[buf][(wv * 16) * 32]);
        gload_lds16(bBase + (size_t)((wv + 4) * 16 + r0) * K + ko, &Bs[buf][((wv + 4) * 16) * 32]);
    };

    stage(0, 0);
    __syncthreads();
    int buf = 0;
    for (int k0 = 0; k0 < K; k0 += 32, buf ^= 1) {
        if (k0 + 32 < K) stage(buf ^ 1, k0 + 32);
        bf16x8_t af[4], bfr[4];
        #pragma unroll
        for (int mt = 0; mt < 4; mt++)
            af[mt] = *(const bf16x8_t*)&As[buf][(mo + mt * 16 + fr) * 32 + pos];
        #pragma unroll
        for (int nt = 0; nt < 4; nt++)
            bfr[nt] = *(const bf16x8_t*)&Bs[buf][(no + nt * 16 + fr) * 32 + pos];
        #pragma unroll
        for (int mt = 0; mt < 4; mt++)
            #pragma unroll
            for (int nt = 0; nt < 4; nt++)
                acc[mt][nt] = __builtin_amdgcn_mfma_f32_16x16x32_bf16(af[mt], bfr[nt], acc[mt][nt], 0, 0, 0);
        __syncthreads();
    }

    // epilogue: C/D layout col=lane&15, row=(lane>>4)*4+r
    #pragma unroll
    for (int mt = 0; mt < 4; mt++) {
        #pragma unroll
        for (int r = 0; r < 4; r++) {
            int row = bm * 128 + mo + mt * 16 + (lane >> 4) * 4 + r;
            #pragma unroll
            for (int nt = 0; nt < 4; nt++) {
                int col = bn * 128 + no + nt * 16 + (lane & 15);
                float v = acc[mt][nt][r] + bias[col];
                if constexpr (RES) v += res[(size_t)row * N + col];
                if constexpr (OUT_BF16) ((u16*)Cout)[(size_t)row * N + col] = f2bf(v);
                else ((float*)Cout)[(size_t)row * N + col] = v;
            }
        }
    }
}

// ------------------ windowed attention, one block per (window, head) ------------------
// Writes compact bf16 out: [win(512), head(16), 49, 32]
constexpr int QS = 40;  // q/k row stride (u16), padded +8
constexpr int VS = 72;  // vT row stride
constexpr int PS = 72;  // p row stride

__global__ __launch_bounds__(256) void attn_kernel(
        const u16* __restrict__ qkv, const float* __restrict__ rpb,
        u16* __restrict__ aout) {
    __shared__ __align__(16) u16 q_s[64 * QS];
    __shared__ __align__(16) u16 k_s[64 * QS];
    __shared__ __align__(16) u16 vT_s[32 * VS];
    __shared__ __align__(16) u16 p_s[64 * PS];
    const int tid = threadIdx.x, lane = tid & 63, wv = tid >> 6;
    const int wh = blockIdx.x;
    const int head = wh & 15, w = wh >> 4;
    const int b = w >> 6, win = w & 63, bh = win >> 3, bw = win & 7;

    // load q,k padded to 64 rows
    {
        int i = tid >> 2, dc = (tid & 3) * 8;
        if (i < 49) {
            int n = (bh * 7 + i / 7) * Ww + (bw * 7 + i % 7);
            const u16* base = qkv + ((size_t)(b * N_ + n)) * (3 * C_) + head * 32 + dc;
            *(u16x8*)&q_s[i * QS + dc] = *(const u16x8*)(base);
            *(u16x8*)&k_s[i * QS + dc] = *(const u16x8*)(base + C_);
        } else {
            u16x8 z = {0,0,0,0,0,0,0,0};
            *(u16x8*)&q_s[i * QS + dc] = z;
            *(u16x8*)&k_s[i * QS + dc] = z;
        }
    }
    // v transposed: vT[d][i]
    for (int f = tid; f < 64 * 32; f += 256) {
        int i = f >> 5, d = f & 31;
        u16 val = 0;
        if (i < 49) {
            int n = (bh * 7 + i / 7) * Ww + (bw * 7 + i % 7);
            val = qkv[((size_t)(b * N_ + n)) * (3 * C_) + 2 * C_ + head * 32 + d];
        }
        vT_s[d * VS + i] = val;
    }
    __syncthreads();

    // S = q @ k^T (wave wv owns rows wv*16..+16)
    f32x4_t zero = {0.f, 0.f, 0.f, 0.f};
    f32x4_t s[4];
    bf16x8_t aq = *(const bf16x8_t*)&q_s[(wv * 16 + (lane & 15)) * QS + (lane >> 4) * 8];
    #pragma unroll
    for (int nt = 0; nt < 4; nt++) {
        bf16x8_t bk = *(const bf16x8_t*)&k_s[(nt * 16 + (lane & 15)) * QS + (lane >> 4) * 8];
        s[nt] = __builtin_amdgcn_mfma_f32_16x16x32_bf16(aq, bk, zero, 0, 0, 0);
    }

    const float scale = 0.17677669529663687f; // 32^-0.5
    #pragma unroll
    for (int r = 0; r < 4; r++) {
        int row = wv * 16 + (lane >> 4) * 4 + r;
        int qy = row / 7, qx = row - qy * 7;
        float pv[4];
        float m = -1e30f;
        #pragma unroll
        for (int nt = 0; nt < 4; nt++) {
            int col = nt * 16 + (lane & 15);
            float bias;
            if (row < 49 && col < 49) {
                int ky = col / 7, kx = col - ky * 7;
                bias = rpb[((qy - ky + 6) * 13 + (qx - kx + 6)) * NH_ + head];
            } else bias = -1e30f;
            float v = s[nt][r] * scale + bias;
            pv[nt] = v;
            m = fmaxf(m, v);
        }
        #pragma unroll
        for (int off = 1; off < 16; off <<= 1) m = fmaxf(m, __shfl_xor(m, off));
        float sum = 0.f;
        #pragma unroll
        for (int nt = 0; nt < 4; nt++) { pv[nt] = __expf(pv[nt] - m); sum += pv[nt]; }
        #pragma unroll
        for (int off = 1; off < 16; off <<= 1) sum += __shfl_xor(sum, off);
        float inv = 1.0f / sum;
        #pragma unroll
        for (int nt = 0; nt < 4; nt++)
            p_s[row * PS + nt * 16 + (lane & 15)] = f2bf(pv[nt] * inv);
    }
    __syncthreads();

    // O = P @ V (rows wv*16..+16, cols 0..31)
    f32x4_t o[2] = {zero, zero};
    #pragma unroll
    for (int kt = 0; kt < 2; kt++) {
        bf16x8_t ap = *(const bf16x8_t*)&p_s[(wv * 16 + (lane & 15)) * PS + kt * 32 + (lane >> 4) * 8];
        #pragma unroll
        for (int nt = 0; nt < 2; nt++) {
            bf16x8_t bv = *(const bf16x8_t*)&vT_s[(nt * 16 + (lane & 15)) * VS + kt * 32 + (lane >> 4) * 8];
            o[nt] = __builtin_amdgcn_mfma_f32_16x16x32_bf16(ap, bv, o[nt], 0, 0, 0);
        }
    }
    // compact write: aout[((w*16+head)*49 + row)*32 + col]
    u16* obase = aout + ((size_t)(w * 16 + head)) * 49 * 32;
    #pragma unroll
    for (int nt = 0; nt < 2; nt++) {
        #pragma unroll
        for (int r = 0; r < 4; r++) {
            int row = wv * 16 + (lane >> 4) * 4 + r;
            if (row < 49)
                obase[row * 32 + nt * 16 + (lane & 15)] = f2bf(o[nt][r]);
        }
    }
}

// ------------------ window-reverse + residual + LayerNorm2 (fused) ------------------
// x2 = x + window_reverse(aout);  h = LN(x2) in bf16.  One wave per row.
__global__ __launch_bounds__(256) void wrev_ln(const float* __restrict__ x,
        const u16* __restrict__ aout, const float* __restrict__ g,
        const float* __restrict__ bt, float* __restrict__ x2, u16* __restrict__ h) {
    int lane = threadIdx.x & 63, wvv = threadIdx.x >> 6;
    int m = blockIdx.x * 4 + wvv;
    int b = m / N_, n = m - b * N_;
    int iy = n / Ww, ix = n - iy * Ww;
    int w = b * 64 + (iy / 7) * 8 + (ix / 7);
    int pos = (iy % 7) * 7 + (ix % 7);
    int head = lane >> 2, d0 = (lane & 3) * 8;
    u16x8 ao = *(const u16x8*)&aout[(((size_t)w * 16 + head) * 49 + pos) * 32 + d0];
    const float4* xr = (const float4*)(x + (size_t)m * C_ + lane * 8);
    float4 a = xr[0], c = xr[1];
    float v[8];
    v[0] = a.x + bf2f(ao[0]); v[1] = a.y + bf2f(ao[1]);
    v[2] = a.z + bf2f(ao[2]); v[3] = a.w + bf2f(ao[3]);
    v[4] = c.x + bf2f(ao[4]); v[5] = c.y + bf2f(ao[5]);
    v[6] = c.z + bf2f(ao[6]); v[7] = c.w + bf2f(ao[7]);
    float s = 0.f, ss = 0.f;
    #pragma unroll
    for (int j = 0; j < 8; j++) { s += v[j]; ss += v[j] * v[j]; }
    #pragma unroll
    for (int off = 1; off < 64; off <<= 1) {
        s  += __shfl_xor(s, off);
        ss += __shfl_xor(ss, off);
    }
    float mean = s * (1.0f / C_);
    float var  = ss * (1.0f / C_) - mean * mean;
    float rstd = rsqrtf(var + 1e-5f);
    float4 o0 = {v[0], v[1], v[2], v[3]}, o1 = {v[4], v[5], v[6], v[7]};
    float4* x2r = (float4*)(x2 + (size_t)m * C_ + lane * 8);
    x2r[0] = o0; x2r[1] = o1;
    const float4* g4 = (const float4*)(g + lane * 8);
    const float4* b4 = (const float4*)(bt + lane * 8);
    float4 g0 = g4[0], g1 = g4[1], bb0 = b4[0], bb1 = b4[1];
    u16x8 o;
    o[0] = f2bf((v[0] - mean) * rstd * g0.x + bb0.x);
    o[1] = f2bf((v[1] - mean) * rstd * g0.y + bb0.y);
    o[2] = f2bf((v[2] - mean) * rstd * g0.z + bb0.z);
    o[3] = f2bf((v[3] - mean) * rstd * g0.w + bb0.w);
    o[4] = f2bf((v[4] - mean) * rstd * g1.x + bb1.x);
    o[5] = f2bf((v[5] - mean) * rstd * g1.y + bb1.y);
    o[6] = f2bf((v[6] - mean) * rstd * g1.z + bb1.z);
    o[7] = f2bf((v[7] - mean) * rstd * g1.w + bb1.w);
    *(u16x8*)&h[(size_t)m * C_ + lane * 8] = o;
}

// ------------------ depthwise 3x3 conv + bias + exact GELU (y-pair blocked) ------------------
// block = (b, ypair, half); thread t: channels t*8..t*8+7; x in [half*28, half*28+28)
// 4-row register window -> 2 output rows per block (read amplification 3x -> 2x)
__global__ __launch_bounds__(256) void dwconv_gelu(const u16* __restrict__ in,
        const float* __restrict__ w, const float* __restrict__ bias, u16* __restrict__ out) {
    const int t = threadIdx.x;
    const int blk = blockIdx.x;
    const int half = blk & 1;
    const int byp = blk >> 1;
    const int yp = byp % 28;
    const int b = byp / 28;
    const int y0 = yp * 2;
    const int c0 = t * 8;

    float wr[9][8];
    #pragma unroll
    for (int k = 0; k < 9; k++)
        #pragma unroll
        for (int j = 0; j < 8; j++) wr[k][j] = w[(c0 + j) * 9 + k];
    float bs[8];
    #pragma unroll
    for (int j = 0; j < 8; j++) bs[j] = bias[c0 + j];

    u16x8 zerov = {0,0,0,0,0,0,0,0};
    auto ldcol = [&](int xx, u16x8* col) {
        #pragma unroll
        for (int dy = 0; dy < 4; dy++) {
            int yy = y0 + dy - 1;
            bool ok = (yy >= 0 && yy < Hh && xx >= 0 && xx < Ww);
            col[dy] = ok ? *(const u16x8*)&in[(((size_t)b * Hh + yy) * Ww + xx) * HID_ + c0] : zerov;
        }
    };

    int xs = half * 28;
    u16x8 wA[4], wB[4], wC[4];
    ldcol(xs - 1, wA);
    ldcol(xs, wB);
    for (int x = xs; x < xs + 28; x++) {
        ldcol(x + 1, wC);
        float acc0[8], acc1[8];
        #pragma unroll
        for (int j = 0; j < 8; j++) { acc0[j] = bs[j]; acc1[j] = bs[j]; }
        #pragma unroll
        for (int dy = 0; dy < 3; dy++)
            #pragma unroll
            for (int j = 0; j < 8; j++) {
                acc0[j] += bf2f(wA[dy][j]) * wr[dy * 3 + 0][j];
                acc0[j] += bf2f(wB[dy][j]) * wr[dy * 3 + 1][j];
                acc0[j] += bf2f(wC[dy][j]) * wr[dy * 3 + 2][j];
                acc1[j] += bf2f(wA[dy + 1][j]) * wr[dy * 3 + 0][j];
                acc1[j] += bf2f(wB[dy + 1][j]) * wr[dy * 3 + 1][j];
                acc1[j] += bf2f(wC[dy + 1][j]) * wr[dy * 3 + 2][j];
            }
        u16x8 o0, o1;
        #pragma unroll
        for (int j = 0; j < 8; j++) {
            float v0 = acc0[j];
            o0[j] = f2bf(0.5f * v0 * (1.0f + erff(v0 * 0.70710678118654752f)));
            float v1 = acc1[j];
            o1[j] = f2bf(0.5f * v1 * (1.0f + erff(v1 * 0.70710678118654752f)));
        }
        *(u16x8*)&out[(((size_t)b * Hh + y0) * Ww + x) * HID_ + c0] = o0;
        *(u16x8*)&out[(((size_t)b * Hh + y0 + 1) * Ww + x) * HID_ + c0] = o1;
        #pragma unroll
        for (int dy = 0; dy < 4; dy++) { wA[dy] = wB[dy]; wB[dy] = wC[dy]; }
    }
}

// ------------------ launch ------------------
extern "C" void kernel_launch(void* const* d_in, const int* in_sizes, int n_in,
                              void* d_out, int out_size, void* d_ws, size_t ws_size,
                              hipStream_t stream) {
    const float* x    = (const float*)d_in[0];
    const float* n1g  = (const float*)d_in[3];
    const float* n1b  = (const float*)d_in[4];
    const float* n2g  = (const float*)d_in[5];
    const float* n2b  = (const float*)d_in[6];
    const float* qkvw = (const float*)d_in[7];
    const float* qkvb = (const float*)d_in[8];
    const float* rpb  = (const float*)d_in[9];
    const float* fc1w = (const float*)d_in[10];
    const float* fc1b = (const float*)d_in[11];
    const float* dww  = (const float*)d_in[12];
    const float* dwb  = (const float*)d_in[13];
    const float* fc2w = (const float*)d_in[14];
    const float* fc2b = (const float*)d_in[15];

    char* ws = (char*)d_ws;
    // layout (bytes):
    // x2   : [0, 51380224)          fp32 [M,512]
    // h    : [51380224, 77070336)   bf16 [M,512]  (LN1 out, then LN2 out)
    // qkv  : [77070336, 154140672)  bf16 [M,1536]
    // aout : [154140672, +25690112) bf16 [512,16,49,32]  (dead after wrev_ln; fc1 overwrites)
    // f1o  : [154140672, 256901120) bf16 [M,2048]
    // cvo  : [51380224, 154140672)  bf16 [M,2048]  (overwrites h+qkv after fc1)
    // wbf  : [256901120, ...)       bf16 weights
    float* x2  = (float*)(ws);
    u16*   h   = (u16*)(ws + 51380224);
    u16*   qkvo= (u16*)(ws + 77070336);
    u16*   aout= (u16*)(ws + 154140672);
    u16*   f1o = (u16*)(ws + 154140672);
    u16*   cvo = (u16*)(ws + 51380224);
    u16*   wq  = (u16*)(ws + 256901120);
    u16*   w1  = (u16*)(ws + 256901120 + 1572864);
    u16*   w2  = (u16*)(ws + 256901120 + 1572864 + 2097152);

    cvt_w<<<dim3(4096), dim3(256), 0, stream>>>(qkvw, fc1w, fc2w, wq, w1, w2);
    ln_kernel<<<dim3(M_ / 4), dim3(256), 0, stream>>>(x, n1g, n1b, h);
    gemm_bt<false, true><<<dim3(M_ / 128, 1536 / 128), dim3(256), 0, stream>>>(
        h, wq, qkvb, nullptr, (void*)qkvo, M_, 1536, 512);
    attn_kernel<<<dim3(B_ * 64 * NH_), dim3(256), 0, stream>>>(qkvo, rpb, aout);
    wrev_ln<<<dim3(M_ / 4), dim3(256), 0, stream>>>(x, aout, n2g, n2b, x2, h);
    gemm_bt<false, true><<<dim3(M_ / 128, 2048 / 128), dim3(256), 0, stream>>>(
        h, w1, fc1b, nullptr, (void*)f1o, M_, 2048, 512);
    dwconv_gelu<<<dim3(B_ * 28 * 2), dim3(256), 0, stream>>>(f1o, dww, dwb, cvo);
    gemm_bt<true, false><<<dim3(M_ / 128, 512 / 128), dim3(256), 0, stream>>>(
        cvo, w2, fc2b, x2, d_out, M_, 512, 2048);
}

// Round 4
// 541.463 us; speedup vs baseline: 1.1315x; 1.0630x over previous
//
#include <hip/hip_runtime.h>
#include <hip/hip_bf16.h>

typedef unsigned short u16;
typedef unsigned int u32;
typedef __attribute__((ext_vector_type(8))) short bf16x8_t;   // MFMA A/B frag (8 bf16)
typedef __attribute__((ext_vector_type(4))) float f32x4_t;    // MFMA C/D frag
typedef __attribute__((ext_vector_type(8))) u16 u16x8;

// ---- problem constants ----
constexpr int B_  = 8;
constexpr int C_  = 512;
constexpr int NH_ = 16;
constexpr int HID_= 2048;
constexpr int Hh  = 56, Ww = 56;
constexpr int N_  = Hh * Ww;       // 3136
constexpr int M_  = B_ * N_;       // 25088 rows

__device__ __forceinline__ u16 f2bf(float f) {
    u32 u = __float_as_uint(f);
    u32 r = (u + 0x7fffu + ((u >> 16) & 1u)) >> 16;
    return (u16)r;
}
__device__ __forceinline__ float bf2f(u16 v) {
    return __uint_as_float(((u32)v) << 16);
}

__device__ __forceinline__ void gload_lds16(const void* g, void* l) {
    __builtin_amdgcn_global_load_lds(
        (const __attribute__((address_space(1))) u32*)g,
        (__attribute__((address_space(3))) u32*)l, 16, 0, 0);
}

// ------------------ weight fp32 -> bf16 conversion ------------------
__global__ void cvt_w(const float* __restrict__ qkvw, const float* __restrict__ fc1w,
                      const float* __restrict__ fc2w, u16* __restrict__ oq,
                      u16* __restrict__ o1, u16* __restrict__ o2) {
    int i = blockIdx.x * 256 + threadIdx.x;
    if (i < 3 * C_ * C_) oq[i] = f2bf(qkvw[i]);
    if (i < HID_ * C_) { o1[i] = f2bf(fc1w[i]); o2[i] = f2bf(fc2w[i]); }
}

// ------------------ LayerNorm (row=512) -> bf16 ------------------
__global__ __launch_bounds__(256) void ln_kernel(const float* __restrict__ x,
        const float* __restrict__ g, const float* __restrict__ b, u16* __restrict__ out) {
    int lane = threadIdx.x & 63, wv = threadIdx.x >> 6;
    size_t row = (size_t)blockIdx.x * 4 + wv;
    const float4* xr = (const float4*)(x + row * C_);
    float4 a = xr[lane * 2], c = xr[lane * 2 + 1];
    float s  = a.x + a.y + a.z + a.w + c.x + c.y + c.z + c.w;
    float ss = a.x*a.x + a.y*a.y + a.z*a.z + a.w*a.w + c.x*c.x + c.y*c.y + c.z*c.z + c.w*c.w;
    #pragma unroll
    for (int off = 1; off < 64; off <<= 1) {
        s  += __shfl_xor(s, off);
        ss += __shfl_xor(ss, off);
    }
    float mean = s * (1.0f / C_);
    float var  = ss * (1.0f / C_) - mean * mean;
    float rstd = rsqrtf(var + 1e-5f);
    const float4* g4 = (const float4*)g;
    const float4* b4 = (const float4*)b;
    float4 g0 = g4[lane*2], g1 = g4[lane*2+1], b0 = b4[lane*2], b1 = b4[lane*2+1];
    u16x8 o;
    o[0] = f2bf((a.x - mean) * rstd * g0.x + b0.x);
    o[1] = f2bf((a.y - mean) * rstd * g0.y + b0.y);
    o[2] = f2bf((a.z - mean) * rstd * g0.z + b0.z);
    o[3] = f2bf((a.w - mean) * rstd * g0.w + b0.w);
    o[4] = f2bf((c.x - mean) * rstd * g1.x + b1.x);
    o[5] = f2bf((c.y - mean) * rstd * g1.y + b1.y);
    o[6] = f2bf((c.z - mean) * rstd * g1.z + b1.z);
    o[7] = f2bf((c.w - mean) * rstd * g1.w + b1.w);
    *(u16x8*)&out[row * C_ + lane * 8] = o;
}

// ------------------ bf16 GEMM: C[M,N] = A[M,K] @ B[N,K]^T + bias (+res) ------------------
// 128x128 tile, BK=64 as two 32-k planes, single-stage (round-2 structure, measured best).
// XOR-swizzled k-chunks (conflict-free, verified round 2).
// 1-D grid with XCD-cooperative decode: the 4 blocks sharing an A-tile (same bm,
// 4 consecutive bn) get ids congruent mod 8 with adjacent slots -> same XCD,
// dispatched together -> A-tile fetched once into that XCD's L2.
template<bool RES, bool OUT_BF16>
__global__ __launch_bounds__(256) void gemm_bt(
        const u16* __restrict__ A, const u16* __restrict__ B,
        const float* __restrict__ bias, const float* __restrict__ res,
        void* __restrict__ Cout, int M, int N, int K,
        int nbm, int nbn, int nGroups) {
    const int id = blockIdx.x;
    const int xcd = id & 7, slot = id >> 3;
    const int j = slot & 3;
    const int gidx = xcd + 8 * (slot >> 2);
    if (gidx >= nGroups) return;
    const int bm = gidx % nbm;
    const int bn = (gidx / nbm) * 4 + j;
    if (bn >= nbn) return;

    __shared__ __align__(16) u16 As[2 * 128 * 32];
    __shared__ __align__(16) u16 Bs[2 * 128 * 32];
    const int tid = threadIdx.x;
    const int lane = tid & 63;
    const int wv = tid >> 6;

    const int r0 = lane >> 2;                          // staging row within 16-row group
    const int gcb = ((lane & 3) ^ ((lane >> 3) & 3));  // swizzled global chunk for this lane

    const u16* aBase = A + (size_t)(bm * 128) * K;
    const u16* bBase = B + (size_t)(bn * 128) * K;

    f32x4_t acc[4][4];
    f32x4_t zero = {0.f, 0.f, 0.f, 0.f};
    #pragma unroll
    for (int i = 0; i < 4; i++)
        #pragma unroll
        for (int jj = 0; jj < 4; jj++) acc[i][jj] = zero;

    const int mo = (wv >> 1) * 64, no = (wv & 1) * 64;
    const int fr = lane & 15;          // fragment row (m or n)
    const int g4 = lane >> 4;          // k-chunk index within 32-k plane
    const int kkey = (fr >> 1) & 3;    // swizzle key
    const int pos = (g4 ^ kkey) * 8;   // swizzled element offset within row

    for (int k0 = 0; k0 < K; k0 += 64) {
        #pragma unroll
        for (int p = 0; p < 2; p++) {
            const int ko = k0 + p * 32 + gcb * 8;
            gload_lds16(aBase + (size_t)(wv * 16 + r0) * K + ko,       &As[p * 4096 + (wv * 16) * 32]);
            gload_lds16(aBase + (size_t)((wv + 4) * 16 + r0) * K + ko, &As[p * 4096 + ((wv + 4) * 16) * 32]);
            gload_lds16(bBase + (size_t)(wv * 16 + r0) * K + ko,       &Bs[p * 4096 + (wv * 16) * 32]);
            gload_lds16(bBase + (size_t)((wv + 4) * 16 + r0) * K + ko, &Bs[p * 4096 + ((wv + 4) * 16) * 32]);
        }
        __syncthreads();

        #pragma unroll
        for (int ks = 0; ks < 2; ks++) {
            bf16x8_t af[4], bfr[4];
            #pragma unroll
            for (int mt = 0; mt < 4; mt++)
                af[mt] = *(const bf16x8_t*)&As[ks * 4096 + (mo + mt * 16 + fr) * 32 + pos];
            #pragma unroll
            for (int nt = 0; nt < 4; nt++)
                bfr[nt] = *(const bf16x8_t*)&Bs[ks * 4096 + (no + nt * 16 + fr) * 32 + pos];
            #pragma unroll
            for (int mt = 0; mt < 4; mt++)
                #pragma unroll
                for (int nt = 0; nt < 4; nt++)
                    acc[mt][nt] = __builtin_amdgcn_mfma_f32_16x16x32_bf16(af[mt], bfr[nt], acc[mt][nt], 0, 0, 0);
        }
        __syncthreads();
    }

    // epilogue: C/D layout col=lane&15, row=(lane>>4)*4+r
    #pragma unroll
    for (int mt = 0; mt < 4; mt++) {
        #pragma unroll
        for (int r = 0; r < 4; r++) {
            int row = bm * 128 + mo + mt * 16 + (lane >> 4) * 4 + r;
            #pragma unroll
            for (int nt = 0; nt < 4; nt++) {
                int col = bn * 128 + no + nt * 16 + (lane & 15);
                float v = acc[mt][nt][r] + bias[col];
                if constexpr (RES) v += res[(size_t)row * N + col];
                if constexpr (OUT_BF16) ((u16*)Cout)[(size_t)row * N + col] = f2bf(v);
                else ((float*)Cout)[(size_t)row * N + col] = v;
            }
        }
    }
}

// ------------------ windowed attention, one block per (window, head) ------------------
// Writes compact bf16 out: [win(512), head(16), 49, 32]
constexpr int QS = 40;  // q/k row stride (u16), padded +8
constexpr int VS = 72;  // vT row stride
constexpr int PS = 72;  // p row stride

__global__ __launch_bounds__(256) void attn_kernel(
        const u16* __restrict__ qkv, const float* __restrict__ rpb,
        u16* __restrict__ aout) {
    __shared__ __align__(16) u16 q_s[64 * QS];
    __shared__ __align__(16) u16 k_s[64 * QS];
    __shared__ __align__(16) u16 vT_s[32 * VS];
    __shared__ __align__(16) u16 p_s[64 * PS];
    const int tid = threadIdx.x, lane = tid & 63, wv = tid >> 6;
    const int wh = blockIdx.x;
    const int head = wh & 15, w = wh >> 4;
    const int b = w >> 6, win = w & 63, bh = win >> 3, bw = win & 7;

    // load q,k padded to 64 rows
    {
        int i = tid >> 2, dc = (tid & 3) * 8;
        if (i < 49) {
            int n = (bh * 7 + i / 7) * Ww + (bw * 7 + i % 7);
            const u16* base = qkv + ((size_t)(b * N_ + n)) * (3 * C_) + head * 32 + dc;
            *(u16x8*)&q_s[i * QS + dc] = *(const u16x8*)(base);
            *(u16x8*)&k_s[i * QS + dc] = *(const u16x8*)(base + C_);
        } else {
            u16x8 z = {0,0,0,0,0,0,0,0};
            *(u16x8*)&q_s[i * QS + dc] = z;
            *(u16x8*)&k_s[i * QS + dc] = z;
        }
    }
    // v transposed: vT[d][i]
    for (int f = tid; f < 64 * 32; f += 256) {
        int i = f >> 5, d = f & 31;
        u16 val = 0;
        if (i < 49) {
            int n = (bh * 7 + i / 7) * Ww + (bw * 7 + i % 7);
            val = qkv[((size_t)(b * N_ + n)) * (3 * C_) + 2 * C_ + head * 32 + d];
        }
        vT_s[d * VS + i] = val;
    }
    __syncthreads();

    // S = q @ k^T (wave wv owns rows wv*16..+16)
    f32x4_t zero = {0.f, 0.f, 0.f, 0.f};
    f32x4_t s[4];
    bf16x8_t aq = *(const bf16x8_t*)&q_s[(wv * 16 + (lane & 15)) * QS + (lane >> 4) * 8];
    #pragma unroll
    for (int nt = 0; nt < 4; nt++) {
        bf16x8_t bk = *(const bf16x8_t*)&k_s[(nt * 16 + (lane & 15)) * QS + (lane >> 4) * 8];
        s[nt] = __builtin_amdgcn_mfma_f32_16x16x32_bf16(aq, bk, zero, 0, 0, 0);
    }

    const float scale = 0.17677669529663687f; // 32^-0.5
    #pragma unroll
    for (int r = 0; r < 4; r++) {
        int row = wv * 16 + (lane >> 4) * 4 + r;
        int qy = row / 7, qx = row - qy * 7;
        float pv[4];
        float m = -1e30f;
        #pragma unroll
        for (int nt = 0; nt < 4; nt++) {
            int col = nt * 16 + (lane & 15);
            float bias;
            if (row < 49 && col < 49) {
                int ky = col / 7, kx = col - ky * 7;
                bias = rpb[((qy - ky + 6) * 13 + (qx - kx + 6)) * NH_ + head];
            } else bias = -1e30f;
            float v = s[nt][r] * scale + bias;
            pv[nt] = v;
            m = fmaxf(m, v);
        }
        #pragma unroll
        for (int off = 1; off < 16; off <<= 1) m = fmaxf(m, __shfl_xor(m, off));
        float sum = 0.f;
        #pragma unroll
        for (int nt = 0; nt < 4; nt++) { pv[nt] = __expf(pv[nt] - m); sum += pv[nt]; }
        #pragma unroll
        for (int off = 1; off < 16; off <<= 1) sum += __shfl_xor(sum, off);
        float inv = 1.0f / sum;
        #pragma unroll
        for (int nt = 0; nt < 4; nt++)
            p_s[row * PS + nt * 16 + (lane & 15)] = f2bf(pv[nt] * inv);
    }
    __syncthreads();

    // O = P @ V (rows wv*16..+16, cols 0..31)
    f32x4_t o[2] = {zero, zero};
    #pragma unroll
    for (int kt = 0; kt < 2; kt++) {
        bf16x8_t ap = *(const bf16x8_t*)&p_s[(wv * 16 + (lane & 15)) * PS + kt * 32 + (lane >> 4) * 8];
        #pragma unroll
        for (int nt = 0; nt < 2; nt++) {
            bf16x8_t bv = *(const bf16x8_t*)&vT_s[(nt * 16 + (lane & 15)) * VS + kt * 32 + (lane >> 4) * 8];
            o[nt] = __builtin_amdgcn_mfma_f32_16x16x32_bf16(ap, bv, o[nt], 0, 0, 0);
        }
    }
    // compact write: aout[((w*16+head)*49 + row)*32 + col]
    u16* obase = aout + ((size_t)(w * 16 + head)) * 49 * 32;
    #pragma unroll
    for (int nt = 0; nt < 2; nt++) {
        #pragma unroll
        for (int r = 0; r < 4; r++) {
            int row = wv * 16 + (lane >> 4) * 4 + r;
            if (row < 49)
                obase[row * 32 + nt * 16 + (lane & 15)] = f2bf(o[nt][r]);
        }
    }
}

// ------------------ window-reverse + residual + LayerNorm2 (fused) ------------------
// x2 = x + window_reverse(aout);  h = LN(x2) in bf16.  One wave per row.
__global__ __launch_bounds__(256) void wrev_ln(const float* __restrict__ x,
        const u16* __restrict__ aout, const float* __restrict__ g,
        const float* __restrict__ bt, float* __restrict__ x2, u16* __restrict__ h) {
    int lane = threadIdx.x & 63, wvv = threadIdx.x >> 6;
    int m = blockIdx.x * 4 + wvv;
    int b = m / N_, n = m - b * N_;
    int iy = n / Ww, ix = n - iy * Ww;
    int w = b * 64 + (iy / 7) * 8 + (ix / 7);
    int pos = (iy % 7) * 7 + (ix % 7);
    int head = lane >> 2, d0 = (lane & 3) * 8;
    u16x8 ao = *(const u16x8*)&aout[(((size_t)w * 16 + head) * 49 + pos) * 32 + d0];
    const float4* xr = (const float4*)(x + (size_t)m * C_ + lane * 8);
    float4 a = xr[0], c = xr[1];
    float v[8];
    v[0] = a.x + bf2f(ao[0]); v[1] = a.y + bf2f(ao[1]);
    v[2] = a.z + bf2f(ao[2]); v[3] = a.w + bf2f(ao[3]);
    v[4] = c.x + bf2f(ao[4]); v[5] = c.y + bf2f(ao[5]);
    v[6] = c.z + bf2f(ao[6]); v[7] = c.w + bf2f(ao[7]);
    float s = 0.f, ss = 0.f;
    #pragma unroll
    for (int jj = 0; jj < 8; jj++) { s += v[jj]; ss += v[jj] * v[jj]; }
    #pragma unroll
    for (int off = 1; off < 64; off <<= 1) {
        s  += __shfl_xor(s, off);
        ss += __shfl_xor(ss, off);
    }
    float mean = s * (1.0f / C_);
    float var  = ss * (1.0f / C_) - mean * mean;
    float rstd = rsqrtf(var + 1e-5f);
    float4 o0 = {v[0], v[1], v[2], v[3]}, o1 = {v[4], v[5], v[6], v[7]};
    float4* x2r = (float4*)(x2 + (size_t)m * C_ + lane * 8);
    x2r[0] = o0; x2r[1] = o1;
    const float4* g4 = (const float4*)(g + lane * 8);
    const float4* b4 = (const float4*)(bt + lane * 8);
    float4 g0 = g4[0], g1 = g4[1], bb0 = b4[0], bb1 = b4[1];
    u16x8 o;
    o[0] = f2bf((v[0] - mean) * rstd * g0.x + bb0.x);
    o[1] = f2bf((v[1] - mean) * rstd * g0.y + bb0.y);
    o[2] = f2bf((v[2] - mean) * rstd * g0.z + bb0.z);
    o[3] = f2bf((v[3] - mean) * rstd * g0.w + bb0.w);
    o[4] = f2bf((v[4] - mean) * rstd * g1.x + bb1.x);
    o[5] = f2bf((v[5] - mean) * rstd * g1.y + bb1.y);
    o[6] = f2bf((v[6] - mean) * rstd * g1.z + bb1.z);
    o[7] = f2bf((v[7] - mean) * rstd * g1.w + bb1.w);
    *(u16x8*)&h[(size_t)m * C_ + lane * 8] = o;
}

// ------------------ depthwise 3x3 conv + bias + exact GELU (y-pair blocked) ------------------
// block = (b, ypair, xquarter); thread t: channels t*8..t*8+7; x in [xq*14, xq*14+14)
// 4-row register window -> 2 output rows per block (read amplification ~2x)
__global__ __launch_bounds__(256) void dwconv_gelu(const u16* __restrict__ in,
        const float* __restrict__ w, const float* __restrict__ bias, u16* __restrict__ out) {
    const int t = threadIdx.x;
    const int blk = blockIdx.x;
    const int xq = blk & 3;
    const int byp = blk >> 2;
    const int yp = byp % 28;
    const int b = byp / 28;
    const int y0 = yp * 2;
    const int c0 = t * 8;

    float wr[9][8];
    #pragma unroll
    for (int k = 0; k < 9; k++)
        #pragma unroll
        for (int j = 0; j < 8; j++) wr[k][j] = w[(c0 + j) * 9 + k];
    float bs[8];
    #pragma unroll
    for (int j = 0; j < 8; j++) bs[j] = bias[c0 + j];

    u16x8 zerov = {0,0,0,0,0,0,0,0};
    auto ldcol = [&](int xx, u16x8* col) {
        #pragma unroll
        for (int dy = 0; dy < 4; dy++) {
            int yy = y0 + dy - 1;
            bool ok = (yy >= 0 && yy < Hh && xx >= 0 && xx < Ww);
            col[dy] = ok ? *(const u16x8*)&in[(((size_t)b * Hh + yy) * Ww + xx) * HID_ + c0] : zerov;
        }
    };

    int xs = xq * 14;
    u16x8 wA[4], wB[4], wC[4];
    ldcol(xs - 1, wA);
    ldcol(xs, wB);
    for (int x = xs; x < xs + 14; x++) {
        ldcol(x + 1, wC);
        float acc0[8], acc1[8];
        #pragma unroll
        for (int j = 0; j < 8; j++) { acc0[j] = bs[j]; acc1[j] = bs[j]; }
        #pragma unroll
        for (int dy = 0; dy < 3; dy++)
            #pragma unroll
            for (int j = 0; j < 8; j++) {
                acc0[j] += bf2f(wA[dy][j]) * wr[dy * 3 + 0][j];
                acc0[j] += bf2f(wB[dy][j]) * wr[dy * 3 + 1][j];
                acc0[j] += bf2f(wC[dy][j]) * wr[dy * 3 + 2][j];
                acc1[j] += bf2f(wA[dy + 1][j]) * wr[dy * 3 + 0][j];
                acc1[j] += bf2f(wB[dy + 1][j]) * wr[dy * 3 + 1][j];
                acc1[j] += bf2f(wC[dy + 1][j]) * wr[dy * 3 + 2][j];
            }
        u16x8 o0, o1;
        #pragma unroll
        for (int j = 0; j < 8; j++) {
            float v0 = acc0[j];
            o0[j] = f2bf(0.5f * v0 * (1.0f + erff(v0 * 0.70710678118654752f)));
            float v1 = acc1[j];
            o1[j] = f2bf(0.5f * v1 * (1.0f + erff(v1 * 0.70710678118654752f)));
        }
        *(u16x8*)&out[(((size_t)b * Hh + y0) * Ww + x) * HID_ + c0] = o0;
        *(u16x8*)&out[(((size_t)b * Hh + y0 + 1) * Ww + x) * HID_ + c0] = o1;
        #pragma unroll
        for (int dy = 0; dy < 4; dy++) { wA[dy] = wB[dy]; wB[dy] = wC[dy]; }
    }
}

// ------------------ launch ------------------
extern "C" void kernel_launch(void* const* d_in, const int* in_sizes, int n_in,
                              void* d_out, int out_size, void* d_ws, size_t ws_size,
                              hipStream_t stream) {
    const float* x    = (const float*)d_in[0];
    const float* n1g  = (const float*)d_in[3];
    const float* n1b  = (const float*)d_in[4];
    const float* n2g  = (const float*)d_in[5];
    const float* n2b  = (const float*)d_in[6];
    const float* qkvw = (const float*)d_in[7];
    const float* qkvb = (const float*)d_in[8];
    const float* rpb  = (const float*)d_in[9];
    const float* fc1w = (const float*)d_in[10];
    const float* fc1b = (const float*)d_in[11];
    const float* dww  = (const float*)d_in[12];
    const float* dwb  = (const float*)d_in[13];
    const float* fc2w = (const float*)d_in[14];
    const float* fc2b = (const float*)d_in[15];

    char* ws = (char*)d_ws;
    // layout (bytes):
    // x2   : [0, 51380224)          fp32 [M,512]
    // h    : [51380224, 77070336)   bf16 [M,512]  (LN1 out, then LN2 out)
    // qkv  : [77070336, 154140672)  bf16 [M,1536]
    // aout : [154140672, +25690112) bf16 [512,16,49,32]  (dead after wrev_ln; fc1 overwrites)
    // f1o  : [154140672, 256901120) bf16 [M,2048]
    // cvo  : [51380224, 154140672)  bf16 [M,2048]  (overwrites h+qkv after fc1)
    // wbf  : [256901120, ...)       bf16 weights
    float* x2  = (float*)(ws);
    u16*   h   = (u16*)(ws + 51380224);
    u16*   qkvo= (u16*)(ws + 77070336);
    u16*   aout= (u16*)(ws + 154140672);
    u16*   f1o = (u16*)(ws + 154140672);
    u16*   cvo = (u16*)(ws + 51380224);
    u16*   wq  = (u16*)(ws + 256901120);
    u16*   w1  = (u16*)(ws + 256901120 + 1572864);
    u16*   w2  = (u16*)(ws + 256901120 + 1572864 + 2097152);

    // grid size for gemm: 32 * ceil(nGroups / 8), nGroups = nbm * ceil(nbn/4)
    auto ggrid = [](int nGroups) { return 32 * ((nGroups + 7) / 8); };

    cvt_w<<<dim3(4096), dim3(256), 0, stream>>>(qkvw, fc1w, fc2w, wq, w1, w2);
    ln_kernel<<<dim3(M_ / 4), dim3(256), 0, stream>>>(x, n1g, n1b, h);
    // qkv: nbm=196, nbn=12 -> nGroups = 196*3 = 588
    gemm_bt<false, true><<<dim3(ggrid(588)), dim3(256), 0, stream>>>(
        h, wq, qkvb, nullptr, (void*)qkvo, M_, 1536, 512, 196, 12, 588);
    attn_kernel<<<dim3(B_ * 64 * NH_), dim3(256), 0, stream>>>(qkvo, rpb, aout);
    wrev_ln<<<dim3(M_ / 4), dim3(256), 0, stream>>>(x, aout, n2g, n2b, x2, h);
    // fc1: nbm=196, nbn=16 -> nGroups = 196*4 = 784
    gemm_bt<false, true><<<dim3(ggrid(784)), dim3(256), 0, stream>>>(
        h, w1, fc1b, nullptr, (void*)f1o, M_, 2048, 512, 196, 16, 784);
    dwconv_gelu<<<dim3(B_ * 28 * 4), dim3(256), 0, stream>>>(f1o, dww, dwb, cvo);
    // fc2: nbm=196, nbn=4 -> nGroups = 196
    gemm_bt<true, false><<<dim3(ggrid(196)), dim3(256), 0, stream>>>(
        cvo, w2, fc2b, x2, d_out, M_, 512, 2048, 196, 4, 196);
}

// Round 5
// 509.523 us; speedup vs baseline: 1.2024x; 1.0627x over previous
//
#include <hip/hip_runtime.h>
#include <hip/hip_bf16.h>

typedef unsigned short u16;
typedef unsigned int u32;
typedef __attribute__((ext_vector_type(8))) short bf16x8_t;   // MFMA A/B frag (8 bf16)
typedef __attribute__((ext_vector_type(4))) float f32x4_t;    // MFMA C/D frag
typedef __attribute__((ext_vector_type(8))) u16 u16x8;
typedef __attribute__((ext_vector_type(4))) u32 u32x4;

// ---- problem constants ----
constexpr int B_  = 8;
constexpr int C_  = 512;
constexpr int NH_ = 16;
constexpr int HID_= 2048;
constexpr int Hh  = 56, Ww = 56;
constexpr int N_  = Hh * Ww;       // 3136
constexpr int M_  = B_ * N_;       // 25088 rows

__device__ __forceinline__ u16 f2bf(float f) {
    u32 u = __float_as_uint(f);
    u32 r = (u + 0x7fffu + ((u >> 16) & 1u)) >> 16;
    return (u16)r;
}
__device__ __forceinline__ float bf2f(u16 v) {
    return __uint_as_float(((u32)v) << 16);
}

// raw barrier: no implicit vmcnt(0) drain (keeps global loads in flight).
// memory clobber stops the compiler from moving LDS ops across it.
__device__ __forceinline__ void bar_raw() {
    __asm__ __volatile__("s_barrier" ::: "memory");
}
// barrier that first drains LDS ops only (lgkmcnt(0), vmcnt untouched).
// imm encoding gfx9: vmcnt[3:0]=15, expcnt[6:4]=7, lgkmcnt[11:8]=0, vmcnt[15:14]=3
__device__ __forceinline__ void bar_lgkm() {
    __builtin_amdgcn_s_waitcnt(0xc07f);
    __asm__ __volatile__("s_barrier" ::: "memory");
}

// ------------------ weight fp32 -> bf16 conversion ------------------
__global__ void cvt_w(const float* __restrict__ qkvw, const float* __restrict__ fc1w,
                      const float* __restrict__ fc2w, u16* __restrict__ oq,
                      u16* __restrict__ o1, u16* __restrict__ o2) {
    int i = blockIdx.x * 256 + threadIdx.x;
    if (i < 3 * C_ * C_) oq[i] = f2bf(qkvw[i]);
    if (i < HID_ * C_) { o1[i] = f2bf(fc1w[i]); o2[i] = f2bf(fc2w[i]); }
}

// ------------------ LayerNorm (row=512) -> bf16 ------------------
__global__ __launch_bounds__(256) void ln_kernel(const float* __restrict__ x,
        const float* __restrict__ g, const float* __restrict__ b, u16* __restrict__ out) {
    int lane = threadIdx.x & 63, wv = threadIdx.x >> 6;
    size_t row = (size_t)blockIdx.x * 4 + wv;
    const float4* xr = (const float4*)(x + row * C_);
    float4 a = xr[lane * 2], c = xr[lane * 2 + 1];
    float s  = a.x + a.y + a.z + a.w + c.x + c.y + c.z + c.w;
    float ss = a.x*a.x + a.y*a.y + a.z*a.z + a.w*a.w + c.x*c.x + c.y*c.y + c.z*c.z + c.w*c.w;
    #pragma unroll
    for (int off = 1; off < 64; off <<= 1) {
        s  += __shfl_xor(s, off);
        ss += __shfl_xor(ss, off);
    }
    float mean = s * (1.0f / C_);
    float var  = ss * (1.0f / C_) - mean * mean;
    float rstd = rsqrtf(var + 1e-5f);
    const float4* g4 = (const float4*)g;
    const float4* b4 = (const float4*)b;
    float4 g0 = g4[lane*2], g1 = g4[lane*2+1], b0 = b4[lane*2], b1 = b4[lane*2+1];
    u16x8 o;
    o[0] = f2bf((a.x - mean) * rstd * g0.x + b0.x);
    o[1] = f2bf((a.y - mean) * rstd * g0.y + b0.y);
    o[2] = f2bf((a.z - mean) * rstd * g0.z + b0.z);
    o[3] = f2bf((a.w - mean) * rstd * g0.w + b0.w);
    o[4] = f2bf((c.x - mean) * rstd * g1.x + b1.x);
    o[5] = f2bf((c.y - mean) * rstd * g1.y + b1.y);
    o[6] = f2bf((c.z - mean) * rstd * g1.z + b1.z);
    o[7] = f2bf((c.w - mean) * rstd * g1.w + b1.w);
    *(u16x8*)&out[row * C_ + lane * 8] = o;
}

// ------------------ bf16 GEMM: C[M,N] = A[M,K] @ B[N,K]^T + bias (+res) ------------------
// 128x128 tile, BK=64 (two 32-k planes), 4 waves. Staging via global->VGPR->ds_write
// register pipeline: loads for tile k+1 issued before the MFMA block for tile k and
// only waited on at the NEXT ds_write (raw s_barrier keeps vmcnt in flight).
// XOR-swizzled k-chunks (conflict-free, verified). XCD-cooperative 1-D grid decode:
// the 4 blocks sharing an A-tile land on one XCD -> A fetched once into its L2.
template<bool RES, bool OUT_BF16>
__global__ __launch_bounds__(256) void gemm_bt(
        const u16* __restrict__ A, const u16* __restrict__ B,
        const float* __restrict__ bias, const float* __restrict__ res,
        void* __restrict__ Cout, int M, int N, int K,
        int nbm, int nbn, int nGroups) {
    const int id = blockIdx.x;
    const int xcd = id & 7, slot = id >> 3;
    const int j = slot & 3;
    const int gidx = xcd + 8 * (slot >> 2);
    if (gidx >= nGroups) return;
    const int bm = gidx % nbm;
    const int bn = (gidx / nbm) * 4 + j;
    if (bn >= nbn) return;

    __shared__ __align__(16) u16 As[2 * 128 * 32];
    __shared__ __align__(16) u16 Bs[2 * 128 * 32];
    const int tid = threadIdx.x;
    const int lane = tid & 63;
    const int wv = tid >> 6;

    const int r0 = lane >> 2;                          // staging row within 16-row group
    const int gcb = ((lane & 3) ^ ((lane >> 3) & 3));  // swizzled global chunk for this lane

    const u16* aBase = A + (size_t)(bm * 128) * K;
    const u16* bBase = B + (size_t)(bn * 128) * K;

    f32x4_t acc[4][4];
    f32x4_t zero = {0.f, 0.f, 0.f, 0.f};
    #pragma unroll
    for (int i = 0; i < 4; i++)
        #pragma unroll
        for (int jj = 0; jj < 4; jj++) acc[i][jj] = zero;

    const int mo = (wv >> 1) * 64, no = (wv & 1) * 64;
    const int fr = lane & 15;          // fragment row (m or n)
    const int g4 = lane >> 4;          // k-chunk index within 32-k plane
    const int kkey = (fr >> 1) & 3;    // swizzle key
    const int pos = (g4 ^ kkey) * 8;   // swizzled element offset within row

    u32x4 ra[2][2], rb[2][2];
    auto ldissue = [&](int k0) {
        #pragma unroll
        for (int p = 0; p < 2; p++)
            #pragma unroll
            for (int jj = 0; jj < 2; jj++) {
                const int ko = k0 + p * 32 + gcb * 8;
                ra[p][jj] = *(const u32x4*)(aBase + (size_t)((wv + jj * 4) * 16 + r0) * K + ko);
                rb[p][jj] = *(const u32x4*)(bBase + (size_t)((wv + jj * 4) * 16 + r0) * K + ko);
            }
    };
    auto dswrite = [&]() {
        #pragma unroll
        for (int p = 0; p < 2; p++)
            #pragma unroll
            for (int jj = 0; jj < 2; jj++) {
                ((u32x4*)&As[p * 4096 + (wv + jj * 4) * 16 * 32])[lane] = ra[p][jj];
                ((u32x4*)&Bs[p * 4096 + (wv + jj * 4) * 16 * 32])[lane] = rb[p][jj];
            }
    };

    ldissue(0);
    for (int k0 = 0; k0 < K; k0 += 64) {
        dswrite();                 // vmcnt wait lands here (one full iteration after issue)
        bar_lgkm();                // ds_writes visible; global loads stay in flight
        if (k0 + 64 < K) ldissue(k0 + 64);

        #pragma unroll
        for (int ks = 0; ks < 2; ks++) {
            bf16x8_t af[4], bfr[4];
            #pragma unroll
            for (int mt = 0; mt < 4; mt++)
                af[mt] = *(const bf16x8_t*)&As[ks * 4096 + (mo + mt * 16 + fr) * 32 + pos];
            #pragma unroll
            for (int nt = 0; nt < 4; nt++)
                bfr[nt] = *(const bf16x8_t*)&Bs[ks * 4096 + (no + nt * 16 + fr) * 32 + pos];
            #pragma unroll
            for (int mt = 0; mt < 4; mt++)
                #pragma unroll
                for (int nt = 0; nt < 4; nt++)
                    acc[mt][nt] = __builtin_amdgcn_mfma_f32_16x16x32_bf16(af[mt], bfr[nt], acc[mt][nt], 0, 0, 0);
        }
        bar_raw();                 // all waves done reading before next overwrite
    }

    // epilogue: C/D layout col=lane&15, row=(lane>>4)*4+r
    #pragma unroll
    for (int mt = 0; mt < 4; mt++) {
        #pragma unroll
        for (int r = 0; r < 4; r++) {
            int row = bm * 128 + mo + mt * 16 + (lane >> 4) * 4 + r;
            #pragma unroll
            for (int nt = 0; nt < 4; nt++) {
                int col = bn * 128 + no + nt * 16 + (lane & 15);
                float v = acc[mt][nt][r] + bias[col];
                if constexpr (RES) v += res[(size_t)row * N + col];
                if constexpr (OUT_BF16) ((u16*)Cout)[(size_t)row * N + col] = f2bf(v);
                else ((float*)Cout)[(size_t)row * N + col] = v;
            }
        }
    }
}

// ------------------ windowed attention, one block per (window, head) ------------------
// Writes compact bf16 out: [win(512), head(16), 49, 32]
constexpr int QS = 40;  // q/k row stride (u16), padded +8
constexpr int VS = 72;  // vT row stride
constexpr int PS = 72;  // p row stride

__global__ __launch_bounds__(256) void attn_kernel(
        const u16* __restrict__ qkv, const float* __restrict__ rpb,
        u16* __restrict__ aout) {
    __shared__ __align__(16) u16 q_s[64 * QS];
    __shared__ __align__(16) u16 k_s[64 * QS];
    __shared__ __align__(16) u16 vT_s[32 * VS];
    __shared__ __align__(16) u16 p_s[64 * PS];
    const int tid = threadIdx.x, lane = tid & 63, wv = tid >> 6;
    const int wh = blockIdx.x;
    const int head = wh & 15, w = wh >> 4;
    const int b = w >> 6, win = w & 63, bh = win >> 3, bw = win & 7;

    // load q,k padded to 64 rows
    {
        int i = tid >> 2, dc = (tid & 3) * 8;
        if (i < 49) {
            int n = (bh * 7 + i / 7) * Ww + (bw * 7 + i % 7);
            const u16* base = qkv + ((size_t)(b * N_ + n)) * (3 * C_) + head * 32 + dc;
            *(u16x8*)&q_s[i * QS + dc] = *(const u16x8*)(base);
            *(u16x8*)&k_s[i * QS + dc] = *(const u16x8*)(base + C_);
        } else {
            u16x8 z = {0,0,0,0,0,0,0,0};
            *(u16x8*)&q_s[i * QS + dc] = z;
            *(u16x8*)&k_s[i * QS + dc] = z;
        }
    }
    // v transposed: vT[d][i]
    for (int f = tid; f < 64 * 32; f += 256) {
        int i = f >> 5, d = f & 31;
        u16 val = 0;
        if (i < 49) {
            int n = (bh * 7 + i / 7) * Ww + (bw * 7 + i % 7);
            val = qkv[((size_t)(b * N_ + n)) * (3 * C_) + 2 * C_ + head * 32 + d];
        }
        vT_s[d * VS + i] = val;
    }
    __syncthreads();

    // S = q @ k^T (wave wv owns rows wv*16..+16)
    f32x4_t zero = {0.f, 0.f, 0.f, 0.f};
    f32x4_t s[4];
    bf16x8_t aq = *(const bf16x8_t*)&q_s[(wv * 16 + (lane & 15)) * QS + (lane >> 4) * 8];
    #pragma unroll
    for (int nt = 0; nt < 4; nt++) {
        bf16x8_t bk = *(const bf16x8_t*)&k_s[(nt * 16 + (lane & 15)) * QS + (lane >> 4) * 8];
        s[nt] = __builtin_amdgcn_mfma_f32_16x16x32_bf16(aq, bk, zero, 0, 0, 0);
    }

    const float scale = 0.17677669529663687f; // 32^-0.5
    #pragma unroll
    for (int r = 0; r < 4; r++) {
        int row = wv * 16 + (lane >> 4) * 4 + r;
        int qy = row / 7, qx = row - qy * 7;
        float pv[4];
        float m = -1e30f;
        #pragma unroll
        for (int nt = 0; nt < 4; nt++) {
            int col = nt * 16 + (lane & 15);
            float bias;
            if (row < 49 && col < 49) {
                int ky = col / 7, kx = col - ky * 7;
                bias = rpb[((qy - ky + 6) * 13 + (qx - kx + 6)) * NH_ + head];
            } else bias = -1e30f;
            float v = s[nt][r] * scale + bias;
            pv[nt] = v;
            m = fmaxf(m, v);
        }
        #pragma unroll
        for (int off = 1; off < 16; off <<= 1) m = fmaxf(m, __shfl_xor(m, off));
        float sum = 0.f;
        #pragma unroll
        for (int nt = 0; nt < 4; nt++) { pv[nt] = __expf(pv[nt] - m); sum += pv[nt]; }
        #pragma unroll
        for (int off = 1; off < 16; off <<= 1) sum += __shfl_xor(sum, off);
        float inv = 1.0f / sum;
        #pragma unroll
        for (int nt = 0; nt < 4; nt++)
            p_s[row * PS + nt * 16 + (lane & 15)] = f2bf(pv[nt] * inv);
    }
    __syncthreads();

    // O = P @ V (rows wv*16..+16, cols 0..31)
    f32x4_t o[2] = {zero, zero};
    #pragma unroll
    for (int kt = 0; kt < 2; kt++) {
        bf16x8_t ap = *(const bf16x8_t*)&p_s[(wv * 16 + (lane & 15)) * PS + kt * 32 + (lane >> 4) * 8];
        #pragma unroll
        for (int nt = 0; nt < 2; nt++) {
            bf16x8_t bv = *(const bf16x8_t*)&vT_s[(nt * 16 + (lane & 15)) * VS + kt * 32 + (lane >> 4) * 8];
            o[nt] = __builtin_amdgcn_mfma_f32_16x16x32_bf16(ap, bv, o[nt], 0, 0, 0);
        }
    }
    // compact write: aout[((w*16+head)*49 + row)*32 + col]
    u16* obase = aout + ((size_t)(w * 16 + head)) * 49 * 32;
    #pragma unroll
    for (int nt = 0; nt < 2; nt++) {
        #pragma unroll
        for (int r = 0; r < 4; r++) {
            int row = wv * 16 + (lane >> 4) * 4 + r;
            if (row < 49)
                obase[row * 32 + nt * 16 + (lane & 15)] = f2bf(o[nt][r]);
        }
    }
}

// ------------------ window-reverse + residual + LayerNorm2 (fused) ------------------
// x2 = x + window_reverse(aout);  h = LN(x2) in bf16.  One wave per row.
__global__ __launch_bounds__(256) void wrev_ln(const float* __restrict__ x,
        const u16* __restrict__ aout, const float* __restrict__ g,
        const float* __restrict__ bt, float* __restrict__ x2, u16* __restrict__ h) {
    int lane = threadIdx.x & 63, wvv = threadIdx.x >> 6;
    int m = blockIdx.x * 4 + wvv;
    int b = m / N_, n = m - b * N_;
    int iy = n / Ww, ix = n - iy * Ww;
    int w = b * 64 + (iy / 7) * 8 + (ix / 7);
    int pos = (iy % 7) * 7 + (ix % 7);
    int head = lane >> 2, d0 = (lane & 3) * 8;
    u16x8 ao = *(const u16x8*)&aout[(((size_t)w * 16 + head) * 49 + pos) * 32 + d0];
    const float4* xr = (const float4*)(x + (size_t)m * C_ + lane * 8);
    float4 a = xr[0], c = xr[1];
    float v[8];
    v[0] = a.x + bf2f(ao[0]); v[1] = a.y + bf2f(ao[1]);
    v[2] = a.z + bf2f(ao[2]); v[3] = a.w + bf2f(ao[3]);
    v[4] = c.x + bf2f(ao[4]); v[5] = c.y + bf2f(ao[5]);
    v[6] = c.z + bf2f(ao[6]); v[7] = c.w + bf2f(ao[7]);
    float s = 0.f, ss = 0.f;
    #pragma unroll
    for (int jj = 0; jj < 8; jj++) { s += v[jj]; ss += v[jj] * v[jj]; }
    #pragma unroll
    for (int off = 1; off < 64; off <<= 1) {
        s  += __shfl_xor(s, off);
        ss += __shfl_xor(ss, off);
    }
    float mean = s * (1.0f / C_);
    float var  = ss * (1.0f / C_) - mean * mean;
    float rstd = rsqrtf(var + 1e-5f);
    float4 o0 = {v[0], v[1], v[2], v[3]}, o1 = {v[4], v[5], v[6], v[7]};
    float4* x2r = (float4*)(x2 + (size_t)m * C_ + lane * 8);
    x2r[0] = o0; x2r[1] = o1;
    const float4* g4 = (const float4*)(g + lane * 8);
    const float4* b4 = (const float4*)(bt + lane * 8);
    float4 g0 = g4[0], g1 = g4[1], bb0 = b4[0], bb1 = b4[1];
    u16x8 o;
    o[0] = f2bf((v[0] - mean) * rstd * g0.x + bb0.x);
    o[1] = f2bf((v[1] - mean) * rstd * g0.y + bb0.y);
    o[2] = f2bf((v[2] - mean) * rstd * g0.z + bb0.z);
    o[3] = f2bf((v[3] - mean) * rstd * g0.w + bb0.w);
    o[4] = f2bf((v[4] - mean) * rstd * g1.x + bb1.x);
    o[5] = f2bf((v[5] - mean) * rstd * g1.y + bb1.y);
    o[6] = f2bf((v[6] - mean) * rstd * g1.z + bb1.z);
    o[7] = f2bf((v[7] - mean) * rstd * g1.w + bb1.w);
    *(u16x8*)&h[(size_t)m * C_ + lane * 8] = o;
}

// ------------------ depthwise 3x3 conv + bias + exact GELU (y-pair blocked) ------------------
// block = (b, ypair, xquarter); thread t: channels t*8..t*8+7; x in [xq*14, xq*14+14)
__global__ __launch_bounds__(256) void dwconv_gelu(const u16* __restrict__ in,
        const float* __restrict__ w, const float* __restrict__ bias, u16* __restrict__ out) {
    const int t = threadIdx.x;
    const int blk = blockIdx.x;
    const int xq = blk & 3;
    const int byp = blk >> 2;
    const int yp = byp % 28;
    const int b = byp / 28;
    const int y0 = yp * 2;
    const int c0 = t * 8;

    float wr[9][8];
    #pragma unroll
    for (int k = 0; k < 9; k++)
        #pragma unroll
        for (int j = 0; j < 8; j++) wr[k][j] = w[(c0 + j) * 9 + k];
    float bs[8];
    #pragma unroll
    for (int j = 0; j < 8; j++) bs[j] = bias[c0 + j];

    u16x8 zerov = {0,0,0,0,0,0,0,0};
    auto ldcol = [&](int xx, u16x8* col) {
        #pragma unroll
        for (int dy = 0; dy < 4; dy++) {
            int yy = y0 + dy - 1;
            bool ok = (yy >= 0 && yy < Hh && xx >= 0 && xx < Ww);
            col[dy] = ok ? *(const u16x8*)&in[(((size_t)b * Hh + yy) * Ww + xx) * HID_ + c0] : zerov;
        }
    };

    int xs = xq * 14;
    u16x8 wA[4], wB[4], wC[4];
    ldcol(xs - 1, wA);
    ldcol(xs, wB);
    for (int x = xs; x < xs + 14; x++) {
        ldcol(x + 1, wC);
        float acc0[8], acc1[8];
        #pragma unroll
        for (int j = 0; j < 8; j++) { acc0[j] = bs[j]; acc1[j] = bs[j]; }
        #pragma unroll
        for (int dy = 0; dy < 3; dy++)
            #pragma unroll
            for (int j = 0; j < 8; j++) {
                acc0[j] += bf2f(wA[dy][j]) * wr[dy * 3 + 0][j];
                acc0[j] += bf2f(wB[dy][j]) * wr[dy * 3 + 1][j];
                acc0[j] += bf2f(wC[dy][j]) * wr[dy * 3 + 2][j];
                acc1[j] += bf2f(wA[dy + 1][j]) * wr[dy * 3 + 0][j];
                acc1[j] += bf2f(wB[dy + 1][j]) * wr[dy * 3 + 1][j];
                acc1[j] += bf2f(wC[dy + 1][j]) * wr[dy * 3 + 2][j];
            }
        u16x8 o0, o1;
        #pragma unroll
        for (int j = 0; j < 8; j++) {
            float v0 = acc0[j];
            o0[j] = f2bf(0.5f * v0 * (1.0f + erff(v0 * 0.70710678118654752f)));
            float v1 = acc1[j];
            o1[j] = f2bf(0.5f * v1 * (1.0f + erff(v1 * 0.70710678118654752f)));
        }
        *(u16x8*)&out[(((size_t)b * Hh + y0) * Ww + x) * HID_ + c0] = o0;
        *(u16x8*)&out[(((size_t)b * Hh + y0 + 1) * Ww + x) * HID_ + c0] = o1;
        #pragma unroll
        for (int dy = 0; dy < 4; dy++) { wA[dy] = wB[dy]; wB[dy] = wC[dy]; }
    }
}

// ------------------ launch ------------------
extern "C" void kernel_launch(void* const* d_in, const int* in_sizes, int n_in,
                              void* d_out, int out_size, void* d_ws, size_t ws_size,
                              hipStream_t stream) {
    const float* x    = (const float*)d_in[0];
    const float* n1g  = (const float*)d_in[3];
    const float* n1b  = (const float*)d_in[4];
    const float* n2g  = (const float*)d_in[5];
    const float* n2b  = (const float*)d_in[6];
    const float* qkvw = (const float*)d_in[7];
    const float* qkvb = (const float*)d_in[8];
    const float* rpb  = (const float*)d_in[9];
    const float* fc1w = (const float*)d_in[10];
    const float* fc1b = (const float*)d_in[11];
    const float* dww  = (const float*)d_in[12];
    const float* dwb  = (const float*)d_in[13];
    const float* fc2w = (const float*)d_in[14];
    const float* fc2b = (const float*)d_in[15];

    char* ws = (char*)d_ws;
    // layout (bytes):
    // x2   : [0, 51380224)          fp32 [M,512]
    // h    : [51380224, 77070336)   bf16 [M,512]  (LN1 out, then LN2 out)
    // qkv  : [77070336, 154140672)  bf16 [M,1536]
    // aout : [154140672, +25690112) bf16 [512,16,49,32]  (dead after wrev_ln; fc1 overwrites)
    // f1o  : [154140672, 256901120) bf16 [M,2048]
    // cvo  : [51380224, 154140672)  bf16 [M,2048]  (overwrites h+qkv after fc1)
    // wbf  : [256901120, ...)       bf16 weights
    float* x2  = (float*)(ws);
    u16*   h   = (u16*)(ws + 51380224);
    u16*   qkvo= (u16*)(ws + 77070336);
    u16*   aout= (u16*)(ws + 154140672);
    u16*   f1o = (u16*)(ws + 154140672);
    u16*   cvo = (u16*)(ws + 51380224);
    u16*   wq  = (u16*)(ws + 256901120);
    u16*   w1  = (u16*)(ws + 256901120 + 1572864);
    u16*   w2  = (u16*)(ws + 256901120 + 1572864 + 2097152);

    // grid size for gemm: 32 * ceil(nGroups / 8), nGroups = nbm * ceil(nbn/4)
    auto ggrid = [](int nGroups) { return 32 * ((nGroups + 7) / 8); };

    cvt_w<<<dim3(4096), dim3(256), 0, stream>>>(qkvw, fc1w, fc2w, wq, w1, w2);
    ln_kernel<<<dim3(M_ / 4), dim3(256), 0, stream>>>(x, n1g, n1b, h);
    // qkv: nbm=196, nbn=12 -> nGroups = 196*3 = 588
    gemm_bt<false, true><<<dim3(ggrid(588)), dim3(256), 0, stream>>>(
        h, wq, qkvb, nullptr, (void*)qkvo, M_, 1536, 512, 196, 12, 588);
    attn_kernel<<<dim3(B_ * 64 * NH_), dim3(256), 0, stream>>>(qkvo, rpb, aout);
    wrev_ln<<<dim3(M_ / 4), dim3(256), 0, stream>>>(x, aout, n2g, n2b, x2, h);
    // fc1: nbm=196, nbn=16 -> nGroups = 196*4 = 784
    gemm_bt<false, true><<<dim3(ggrid(784)), dim3(256), 0, stream>>>(
        h, w1, fc1b, nullptr, (void*)f1o, M_, 2048, 512, 196, 16, 784);
    dwconv_gelu<<<dim3(B_ * 28 * 4), dim3(256), 0, stream>>>(f1o, dww, dwb, cvo);
    // fc2: nbm=196, nbn=4 -> nGroups = 196
    gemm_bt<true, false><<<dim3(ggrid(196)), dim3(256), 0, stream>>>(
        cvo, w2, fc2b, x2, d_out, M_, 512, 2048, 196, 4, 196);
}